// Round 18
// baseline (136.163 us; speedup 1.0000x reference)
//
#include <hip/hip_runtime.h>
#include <hip/hip_bf16.h>
#include <stdint.h>
#include <math.h>

typedef __bf16 bf16;
typedef __bf16 bf16x8 __attribute__((ext_vector_type(8)));
typedef float f32x4 __attribute__((ext_vector_type(4)));
typedef short s4 __attribute__((ext_vector_type(4)));  // 4 bf16 (2 VGPR)

#define QSCALE 0.1803368801111f  /* 0.125 * log2(e) */

// B=8, N=1025 (32*32+1), DIM=512, HEADS=12, DH=64, INNER=768
// M = 8*1025 = 8200, padded to 8320. KV per (b,h): 1025 = 16*64 + 1 -> 16 full
// tiles + rank-1 tail (kv=1024) handled in-register.
// V layout "vP": per head [kvq=272][d=64][e=4], kv = kvq*4+e.
// PV uses mfma_f32_16x16x16_bf16 whose A-fragment (lane: A[l15][4*l4+e])
// exactly matches the swapped-QK^T P ownership; no cross-lane P movement.
// Softmax: shift-free (scores exp2-domain max ~8.3 -> p<=~300, FP-safe).
// Denominator l = P·ones computed ON THE MATRIX PIPE (one extra mfma per jt
// with a constant all-ones B operand) -> no VALU adds, no cross-lane reduce.
// ROUND-16 LESSON: V must stay LDS-staged — direct-from-global V exposed L2
// latency on the PV path (56.5us -> 81us). Do not retry.

__device__ __forceinline__ void gload_lds16(const void* g, void* l) {
  typedef const __attribute__((address_space(1))) char g_char;
  typedef __attribute__((address_space(3))) char l_char;
  g_char* gp = (g_char*)(uintptr_t)g;
  l_char* lp = (l_char*)(uint32_t)(uintptr_t)l;
  __builtin_amdgcn_global_load_lds(gp, lp, 16, 0, 0);
}

__device__ __forceinline__ float fexp2(float x) {
#if __has_builtin(__builtin_amdgcn_exp2f)
  return __builtin_amdgcn_exp2f(x);
#else
  return exp2f(x);
#endif
}

__device__ __forceinline__ float frcp(float x) {
#if __has_builtin(__builtin_amdgcn_rcpf)
  return __builtin_amdgcn_rcpf(x);
#else
  return 1.f / x;
#endif
}

__device__ __forceinline__ uint32_t pk2(float a, float b) {
  union { bf16 h; unsigned short u; } ua, ub;
  ua.h = (bf16)a; ub.h = (bf16)b;
  return (uint32_t)ua.u | ((uint32_t)ub.u << 16);
}

__device__ __forceinline__ f32x4 pv_mfma(s4 a, s4 b, f32x4 c) {
#if __has_builtin(__builtin_amdgcn_mfma_f32_16x16x16bf16_1k)
  return __builtin_amdgcn_mfma_f32_16x16x16bf16_1k(a, b, c, 0, 0, 0);
#else
  asm volatile("v_mfma_f32_16x16x16_bf16 %0, %1, %2, %0" : "+v"(c) : "v"(a), "v"(b));
  return c;
#endif
}

// FUSED prep + depthwise conv. Blocks [0,5696): x->xb (pad to 8320 rows),
// w_qkv->bf16, w_out->bf16. Blocks [5696,7744): 3x3 depthwise conv (SAME) +
// cls passthrough -> locb (B,1025,512) bf16, no RMW (added in k_flash).
__global__ __launch_bounds__(256) void k_prep(const float* __restrict__ x,
                                              const float* __restrict__ wqkv,
                                              const float* __restrict__ wout,
                                              bf16* __restrict__ xb, bf16* __restrict__ wqkvb,
                                              bf16* __restrict__ woutb,
                                              const float* __restrict__ wdw,
                                              bf16* __restrict__ locb) {
  if (blockIdx.x >= 5696) {
    const int lb = blockIdx.x - 5696;          // 0..2047
    const int b = lb >> 8;
    const int y = (lb >> 3) & 31;
    const int xseg = lb & 7;
    const int c = threadIdx.x * 2;
    const int x0 = xseg * 4;
    const bool hm = (y > 0), hp = (y < 31);
    float wa[9], wb[9];
#pragma unroll
    for (int k = 0; k < 9; ++k) {
      wa[k] = wdw[(size_t)c * 9 + k];
      wb[k] = wdw[(size_t)(c + 1) * 9 + k];
    }
    const float* xrow = x + ((size_t)b * 1025 + 1) * 512 + c;
    float A0 = 0.f, B0 = 0.f, A1 = 0.f, B1 = 0.f;
    for (int cc = x0 - 1; cc <= x0 + 4; ++cc) {
      float2 v0 = make_float2(0.f, 0.f), v1 = v0, v2 = v0;
      if (cc >= 0 && cc < 32) {
        v1 = *(const float2*)&xrow[((size_t)y * 32 + cc) * 512];
        if (hm) v0 = *(const float2*)&xrow[((size_t)(y - 1) * 32 + cc) * 512];
        if (hp) v2 = *(const float2*)&xrow[((size_t)(y + 1) * 32 + cc) * 512];
      }
      float t0a = v0.x * wa[0] + v1.x * wa[3] + v2.x * wa[6];
      float t1a = v0.x * wa[1] + v1.x * wa[4] + v2.x * wa[7];
      float t2a = v0.x * wa[2] + v1.x * wa[5] + v2.x * wa[8];
      float t0b = v0.y * wb[0] + v1.y * wb[3] + v2.y * wb[6];
      float t1b = v0.y * wb[1] + v1.y * wb[4] + v2.y * wb[7];
      float t2b = v0.y * wb[2] + v1.y * wb[5] + v2.y * wb[8];
      int oc = cc - 1;
      if (oc >= x0 && oc <= x0 + 3) {
        size_t o = ((size_t)b * 1025 + 1 + y * 32 + oc) * 512 + c;
        *(uint32_t*)&locb[o] = pk2(A0 + t2a, A1 + t2b);
      }
      A0 = B0 + t1a; B0 = t0a;
      A1 = B1 + t1b; B1 = t0b;
    }
    if (y == 0 && xseg == 0) {
      float2 xc = *(const float2*)&x[((size_t)b * 1025) * 512 + c];
      *(uint32_t*)&locb[((size_t)b * 1025) * 512 + c] = pk2(xc.x, xc.y);
    }
    return;
  }
  int i = blockIdx.x * 256 + threadIdx.x;
  const float* src = nullptr;
  bf16* dst = nullptr;
  int q = i;
  bool zero = false;
  if (i < 1064960) {
    if (i < 1049600) src = x; else zero = true;
    dst = xb;
  } else if (i < 1064960 + 294912) {
    q = i - 1064960; src = wqkv; dst = wqkvb;
  } else {
    q = i - (1064960 + 294912); src = wout; dst = woutb;
  }
  float4 v = make_float4(0.f, 0.f, 0.f, 0.f);
  if (!zero) v = *(const float4*)&src[(size_t)q * 4];
  uint2 p;
  p.x = pk2(v.x, v.y);
  p.y = pk2(v.z, v.w);
  *(uint2*)&dst[(size_t)q * 4] = p;
}

// Tiled bf16 GEMM, 3-STAGE pipeline (T3+T4): BK=32, triple-buffered LDS,
// counted vmcnt (next stage's LOADS stay in flight) -> prefetch distance 2.
// Chunk swizzle (row>>1)&3. Bijective XCD-chunked 1D grid (m204).
// SWAPPED-OPERAND epilogue: reg r = 4 consecutive CHANNELS, lane l15 = M-row.
// EPI=0 (64x128, NTN=18): scatter q/k (q pre-scaled), V into vP. Grid 2340;
//   LDS 36KB -> 4 blocks/CU (round-15's 128x128/48KB sat at 3/CU: capacity
//   768 < grid 1170 -> 1.52x quantization tail; 64x128 gives 1024 cap, 1.14x).
// EPI=1 (64x64, NTN=8): +bias, fp32 out, row<8200. Grid 1040; 24KB -> 6/CU.
template <int EPI, int BM, int BN, int NTN>
__global__ __launch_bounds__(256) void k_gemm(const bf16* __restrict__ A,
                                              const bf16* __restrict__ Bt, int K,
                                              bf16* __restrict__ q, bf16* __restrict__ kk,
                                              bf16* __restrict__ vt,
                                              const float* __restrict__ bias,
                                              float* __restrict__ out) {
  __shared__ __attribute__((aligned(16))) bf16 sA[3][BM * 32];
  __shared__ __attribute__((aligned(16))) bf16 sB[3][BN * 32];
  constexpr int WROWS = BM / 2, WCOLS = BN / 2;
  constexpr int MF = WROWS / 16, NF = WCOLS / 16;
  constexpr int LOADS = BM / 64 + BN / 64;  // gload_lds16 per wave per stage
  const int tid = threadIdx.x;
  const int lane = tid & 63;
  const int w = tid >> 6;
  const int wr = w >> 1, wc = w & 1;
  const int l15 = lane & 15, l4 = lane >> 4;

  const int nwg = gridDim.x;
  const int qq = nwg >> 3, rr = nwg & 7;
  const int xcd = blockIdx.x & 7, idx = blockIdx.x >> 3;
  const int logical = (xcd < rr) ? xcd * (qq + 1) + idx
                                 : rr * (qq + 1) + (xcd - rr) * qq + idx;
  const int tm = logical / NTN, tn = logical - tm * NTN;

  f32x4 acc[MF][NF] = {};

  const int srow = lane >> 2, schunk = lane & 3;
  const int rA = w * (BM / 4) + srow;
  const bf16* aS = A + ((size_t)(tm * BM + rA)) * K + ((schunk ^ ((rA >> 1) & 3)) * 8);
  const int rB = w * (BN / 4) + srow;
  const bf16* bS = Bt + ((size_t)(tn * BN + rB)) * K + ((schunk ^ ((rB >> 1) & 3)) * 8);

  auto STAGE = [&](int bi, int kt) {
    size_t o = (size_t)kt * 32;
#pragma unroll
    for (int i = 0; i < BM / 64; ++i)
      gload_lds16(aS + (size_t)i * 16 * K + o, &sA[bi][(w * (BM / 4) + i * 16) * 32]);
#pragma unroll
    for (int i = 0; i < BN / 64; ++i)
      gload_lds16(bS + (size_t)i * 16 * K + o, &sB[bi][(w * (BN / 4) + i * 16) * 32]);
  };

  STAGE(0, 0);
  STAGE(1, 1);
  int cur = 0;
  const int Ksteps = K >> 5;
  for (int kt = 0; kt < Ksteps; ++kt) {
    if (kt + 1 < Ksteps) {
      if constexpr (LOADS == 4)      asm volatile("s_waitcnt vmcnt(4)" ::: "memory");
      else if constexpr (LOADS == 3) asm volatile("s_waitcnt vmcnt(3)" ::: "memory");
      else                           asm volatile("s_waitcnt vmcnt(2)" ::: "memory");
    } else {
      asm volatile("s_waitcnt vmcnt(0)" ::: "memory");
    }
    __builtin_amdgcn_s_barrier();
    __builtin_amdgcn_sched_barrier(0);
    if (kt + 2 < Ksteps) {
      int b2 = cur + 2; if (b2 >= 3) b2 -= 3;
      STAGE(b2, kt + 2);
    }

    const bf16* a_ = sA[cur];
    const bf16* b_ = sB[cur];
    bf16x8 af[MF], bfr[NF];
#pragma unroll
    for (int mf = 0; mf < MF; ++mf) {
      int row = wr * WROWS + mf * 16 + l15;
      int phys = l4 ^ ((row >> 1) & 3);
      af[mf] = *(const bf16x8*)&a_[row * 32 + phys * 8];
    }
#pragma unroll
    for (int nf = 0; nf < NF; ++nf) {
      int row = wc * WCOLS + nf * 16 + l15;
      int phys = l4 ^ ((row >> 1) & 3);
      bfr[nf] = *(const bf16x8*)&b_[row * 32 + phys * 8];
    }
    __builtin_amdgcn_s_setprio(1);
#pragma unroll
    for (int mf = 0; mf < MF; ++mf)
#pragma unroll
      for (int nf = 0; nf < NF; ++nf)
        acc[mf][nf] =
            __builtin_amdgcn_mfma_f32_16x16x32_bf16(bfr[nf], af[mf], acc[mf][nf], 0, 0, 0);
    __builtin_amdgcn_s_setprio(0);
    ++cur; if (cur >= 3) cur = 0;
  }

  const int RbaseL = tm * BM + wr * WROWS + l15;
  const int CbaseL = tn * BN + wc * WCOLS + l4 * 4;
#pragma unroll
  for (int mf = 0; mf < MF; ++mf) {
    int R = RbaseL + mf * 16;
    if (R >= 8200) continue;
    if (EPI == 0) {
      int b = R / 1025;
      int n = R - b * 1025;
      int kvq = n >> 2, e = n & 3;
#pragma unroll
      for (int nf = 0; nf < NF; ++nf) {
        int Cc0 = CbaseL + nf * 16;                 // 4-aligned; 4 vals same seg
        int seg = (Cc0 >= 1536) ? 2 : (Cc0 >= 768 ? 1 : 0);
        int inner = Cc0 - seg * 768;
        int h = inner >> 6, d0 = inner & 63;        // d0..d0+3 within same head
        if (seg == 2) {
          bf16* vb = &vt[(((size_t)(b * 12 + h) * 272 + kvq) * 64 + d0) * 4 + e];
#pragma unroll
          for (int r = 0; r < 4; ++r) vb[r * 4] = (bf16)acc[mf][nf][r];
        } else {
          bf16* dst = seg ? kk : q;
          float scl = seg ? 1.f : QSCALE;
          uint2 p;
          p.x = pk2(acc[mf][nf][0] * scl, acc[mf][nf][1] * scl);
          p.y = pk2(acc[mf][nf][2] * scl, acc[mf][nf][3] * scl);
          *(uint2*)&dst[(((size_t)b * 12 + h) * 1088 + n) * 64 + d0] = p;
        }
      }
    } else {
#pragma unroll
      for (int nf = 0; nf < NF; ++nf) {
        int Cc0 = CbaseL + nf * 16;
        float4 bz = *(const float4*)&bias[Cc0];
        float4 o4;
        o4.x = acc[mf][nf][0] + bz.x;
        o4.y = acc[mf][nf][1] + bz.y;
        o4.z = acc[mf][nf][2] + bz.z;
        o4.w = acc[mf][nf][3] + bz.w;
        *(float4*)&out[(size_t)R * 512 + Cc0] = o4;
      }
    }
  }
}

// Flash attention, swapped-QK^T, double-buffered K/V, shift-free softmax.
// 16 full KV tiles + rank-1 tail. PV via mfma_16x16x16 (P in-register).
// Denominator via ones-column MFMA: oaS[r] = sum_kv P(q=4*l4+r, kv).
// Epilogue fuses the depthwise-conv local branch: adds locb for heads h<8.
// LDS = 32768 B. Grid 1632 (XCD-contiguous heads).
// NOTE: do NOT add a min-waves launch_bounds here — (256,4) capped VGPRs and
// caused 250 MB of scratch spill (round 4: 77us -> 151us).
__global__ __launch_bounds__(256) void k_flash(const bf16* __restrict__ qg,
                                               const bf16* __restrict__ kg,
                                               const bf16* __restrict__ vpg,
                                               const bf16* __restrict__ locb,
                                               bf16* __restrict__ outb) {
  __shared__ __attribute__((aligned(16))) bf16 sK[2][64 * 64];
  __shared__ __attribute__((aligned(16))) bf16 sVP[2][16 * 256];  // 16 kvq x 64 d x 4 e
  const int tid = threadIdx.x, lane = tid & 63, w = tid >> 6;
  const int l15 = lane & 15, l4 = lane >> 4;
  const int wg = blockIdx.x;
  const int logical = (wg & 7) * 204 + (wg >> 3);
  const int bh = logical / 17, qgp = logical - bh * 17;
  const int b = bh / 12, h = bh - b * 12;
  const int srow = lane >> 3, sslot = lane & 7;

  size_t qoff = ((size_t)bh * 1088 + qgp * 64 + w * 16 + l15) * 64 + l4 * 8;
  const bf16x8 qf0 = *(const bf16x8*)&qg[qoff];
  const bf16x8 qf1 = *(const bf16x8*)&qg[qoff + 32];

  f32x4 oa[4] = {};
  f32x4 oaS = {};  // denominator accumulator (P · ones)
  union { uint32_t u[2]; s4 v; } ones;
  ones.u[0] = 0x3f803f80u;  // two bf16 1.0
  ones.u[1] = 0x3f803f80u;

  const int px0 = (l4 ^ (l15 & 7)) * 8;
  const int px1 = ((4 + l4) ^ (l15 & 7)) * 8;

  const int rowA = w * 16 + srow, rowB = rowA + 8;
  const int clogA = sslot ^ (rowA & 7), clogB = sslot ^ (rowB & 7);
  const bf16* kS1 = kg + ((size_t)bh * 1088 + rowA) * 64 + clogA * 8;
  const bf16* kS2 = kg + ((size_t)bh * 1088 + rowB) * 64 + clogB * 8;
  const bf16* vS1 = vpg + (size_t)bh * 69632 + w * 1024 + lane * 8;
  const bf16* vS2 = vS1 + 512;
  const int kD1 = rowA * 64, kD2 = rowB * 64;
  const int vD1 = w * 1024 + lane * 8, vD2 = vD1 + 512;

  auto STAGE = [&](int bi, int t) {
    size_t o = (size_t)t * 4096;
    gload_lds16(kS1 + o, &sK[bi][kD1]);
    gload_lds16(kS2 + o, &sK[bi][kD2]);
    gload_lds16(vS1 + o, &sVP[bi][vD1]);
    gload_lds16(vS2 + o, &sVP[bi][vD2]);
  };

  STAGE(0, 0);
  int cur = 0;

  for (int t = 0; t < 16; ++t) {
    asm volatile("s_waitcnt vmcnt(0)" ::: "memory");
    __builtin_amdgcn_s_barrier();
    __builtin_amdgcn_sched_barrier(0);
    if (t < 15) STAGE(cur ^ 1, t + 1);

    const bf16* kb_ = sK[cur];
    const bf16* vpb = sVP[cur];

    f32x4 sc[4] = {};
    __builtin_amdgcn_s_setprio(1);
#pragma unroll
    for (int jt = 0; jt < 4; ++jt) {
      bf16x8 a0 = *(const bf16x8*)&kb_[(jt * 16 + l15) * 64 + px0];
      sc[jt] = __builtin_amdgcn_mfma_f32_16x16x32_bf16(a0, qf0, sc[jt], 0, 0, 0);
    }
#pragma unroll
    for (int jt = 0; jt < 4; ++jt) {
      bf16x8 a1 = *(const bf16x8*)&kb_[(jt * 16 + l15) * 64 + px1];
      sc[jt] = __builtin_amdgcn_mfma_f32_16x16x32_bf16(a1, qf1, sc[jt], 0, 0, 0);
    }
    __builtin_amdgcn_s_setprio(0);

    union { uint32_t u[2]; s4 v; } pa[4];
#pragma unroll
    for (int jt = 0; jt < 4; ++jt) {
      float p0 = fexp2(sc[jt][0]);
      float p1 = fexp2(sc[jt][1]);
      float p2 = fexp2(sc[jt][2]);
      float p3 = fexp2(sc[jt][3]);
      pa[jt].u[0] = pk2(p0, p1);
      pa[jt].u[1] = pk2(p2, p3);
    }

    __builtin_amdgcn_s_setprio(1);
#pragma unroll
    for (int jt = 0; jt < 4; ++jt) {
#pragma unroll
      for (int db = 0; db < 4; ++db) {
        s4 vf = *(const s4*)&vpb[((jt * 4 + l4) * 64 + db * 16 + l15) * 4];
        oa[db] = pv_mfma(pa[jt].v, vf, oa[db]);
      }
      oaS = pv_mfma(pa[jt].v, ones.v, oaS);  // denominator on the matrix pipe
    }
    __builtin_amdgcn_s_setprio(0);
    cur ^= 1;
  }

  // Rank-1 tail: kv = 1024.
  {
    const bf16* k1 = kg + ((size_t)bh * 1088 + 1024) * 64;
    bf16x8 kA = *(const bf16x8*)&k1[l4 * 8];
    bf16x8 kB = *(const bf16x8*)&k1[32 + l4 * 8];
    float s = 0.f;
#pragma unroll
    for (int e = 0; e < 8; ++e)
      s += (float)qf0[e] * (float)kA[e] + (float)qf1[e] * (float)kB[e];
    s += __shfl_xor(s, 16);
    s += __shfl_xor(s, 32);
    float p = fexp2(s);
    float pr[4];
#pragma unroll
    for (int r = 0; r < 4; ++r) pr[r] = __shfl(p, l4 * 4 + r);
    const bf16* v1 = vpg + (size_t)bh * 69632 + 65536;  // kvq=256, e=0
#pragma unroll
    for (int db = 0; db < 4; ++db) {
      float vd = (float)v1[(db * 16 + l15) * 4];
#pragma unroll
      for (int r = 0; r < 4; ++r) oa[db][r] += pr[r] * vd;
    }
#pragma unroll
    for (int r = 0; r < 4; ++r) oaS[r] += pr[r];
  }

#pragma unroll
  for (int r = 0; r < 4; ++r) {
    float ir = frcp(oaS[r]);  // per-lane: oaS[r] = l[q = l4*4 + r]
    int n = qgp * 64 + w * 16 + l4 * 4 + r;
    if (n >= 1025) continue;
#pragma unroll
    for (int db = 0; db < 4; ++db) {
      float v = oa[db][r] * ir;
      if (h < 8)
        v += (float)locb[((size_t)b * 1025 + n) * 512 + h * 64 + db * 16 + l15];
      outb[((size_t)b * 1025 + n) * 768 + h * 64 + db * 16 + l15] = (bf16)v;
    }
  }
}

extern "C" void kernel_launch(void* const* d_in, const int* in_sizes, int n_in,
                              void* d_out, int out_size, void* d_ws, size_t ws_size,
                              hipStream_t stream) {
  const float* x = (const float*)d_in[0];
  const float* w_qkv = (const float*)d_in[1];
  const float* w_dw = (const float*)d_in[2];
  const float* w_out = (const float*)d_in[3];
  const float* b_out = (const float*)d_in[4];
  float* out = (float*)d_out;

  char* ws = (char*)d_ws;
  size_t off = 0;
  auto alloc = [&](size_t bytes) {
    char* p = ws + off;
    off = (off + bytes + 255) & ~(size_t)255;
    return p;
  };
  bf16* xb    = (bf16*)alloc((size_t)8320 * 512 * 2);
  bf16* wqkvb = (bf16*)alloc((size_t)2304 * 512 * 2);
  bf16* woutb = (bf16*)alloc((size_t)512 * 768 * 2);
  bf16* qb    = (bf16*)alloc((size_t)96 * 1088 * 64 * 2);
  bf16* kb    = (bf16*)alloc((size_t)96 * 1088 * 64 * 2);
  bf16* vP    = (bf16*)alloc((size_t)96 * 272 * 64 * 4 * 2);  // 69632 elems/head
  bf16* locb  = (bf16*)alloc((size_t)8 * 1025 * 512 * 2);
  bf16* outb  = (bf16*)alloc((size_t)8320 * 768 * 2);

  // Fused prep + conv: 5696 prep blocks + 2048 conv blocks
  k_prep<<<7744, 256, 0, stream>>>(x, w_qkv, w_out, xb, wqkvb, woutb, w_dw, locb);
  // 2340 = 130*18 blocks (64x128 tiles), XCD-chunked inside the kernel
  k_gemm<0, 64, 128, 18><<<2340, 256, 0, stream>>>(xb, wqkvb, 512, qb, kb, vP,
                                                   nullptr, nullptr);
  k_flash<<<1632, 256, 0, stream>>>(qb, kb, vP, locb, outb);
  // 1040 = 130*8 blocks
  k_gemm<1, 64, 64, 8><<<1040, 256, 0, stream>>>(outb, woutb, 768, nullptr, nullptr,
                                                 nullptr, b_out, out);
}

// Round 19
// 135.777 us; speedup vs baseline: 1.0028x; 1.0028x over previous
//
#include <hip/hip_runtime.h>
#include <hip/hip_bf16.h>
#include <stdint.h>
#include <math.h>

typedef __bf16 bf16;
typedef __bf16 bf16x8 __attribute__((ext_vector_type(8)));
typedef float f32x4 __attribute__((ext_vector_type(4)));
typedef short s4 __attribute__((ext_vector_type(4)));  // 4 bf16 (2 VGPR)

#define QSCALE 0.1803368801111f  /* 0.125 * log2(e) */

// B=8, N=1025 (32*32+1), DIM=512, HEADS=12, DH=64, INNER=768
// M = 8*1025 = 8200, padded to 8320. KV per (b,h): 1025 = 16*64 + 1 -> 16 full
// tiles + rank-1 tail (kv=1024) handled in-register.
// V layout "vP": per head [kvq=272][d=64][e=4], kv = kvq*4+e.
// PV uses mfma_f32_16x16x16_bf16 whose A-fragment (lane: A[l15][4*l4+e])
// exactly matches the swapped-QK^T P ownership; no cross-lane P movement.
// Softmax: shift-free (scores exp2-domain max ~8.3 -> p<=~300, FP-safe).
// ROUND-16 LESSON: V fragments must come from LDS (direct per-lane global V
// exposed L2 latency: 56.5->81us). ROUND-18 LESSON: ones-column MFMA for the
// denominator costs more matrix-pipe than the VALU it saves (56.6->58).
// This round: V stays in LDS but SINGLE-buffered (staged at top-of-iter,
// consumed after a second counted-wait barrier) -> LDS 24KB -> 6 blocks/CU
// (capacity 1536 vs grid 1632; the 32KB version capped at 1280 -> ~22% tail).

__device__ __forceinline__ void gload_lds16(const void* g, void* l) {
  typedef const __attribute__((address_space(1))) char g_char;
  typedef __attribute__((address_space(3))) char l_char;
  g_char* gp = (g_char*)(uintptr_t)g;
  l_char* lp = (l_char*)(uint32_t)(uintptr_t)l;
  __builtin_amdgcn_global_load_lds(gp, lp, 16, 0, 0);
}

__device__ __forceinline__ float fexp2(float x) {
#if __has_builtin(__builtin_amdgcn_exp2f)
  return __builtin_amdgcn_exp2f(x);
#else
  return exp2f(x);
#endif
}

__device__ __forceinline__ float frcp(float x) {
#if __has_builtin(__builtin_amdgcn_rcpf)
  return __builtin_amdgcn_rcpf(x);
#else
  return 1.f / x;
#endif
}

__device__ __forceinline__ uint32_t pk2(float a, float b) {
  union { bf16 h; unsigned short u; } ua, ub;
  ua.h = (bf16)a; ub.h = (bf16)b;
  return (uint32_t)ua.u | ((uint32_t)ub.u << 16);
}

__device__ __forceinline__ f32x4 pv_mfma(s4 a, s4 b, f32x4 c) {
#if __has_builtin(__builtin_amdgcn_mfma_f32_16x16x16bf16_1k)
  return __builtin_amdgcn_mfma_f32_16x16x16bf16_1k(a, b, c, 0, 0, 0);
#else
  asm volatile("v_mfma_f32_16x16x16_bf16 %0, %1, %2, %0" : "+v"(c) : "v"(a), "v"(b));
  return c;
#endif
}

// FUSED prep + depthwise conv. Blocks [0,5696): x->xb (pad to 8320 rows),
// w_qkv->bf16, w_out->bf16. Blocks [5696,7744): 3x3 depthwise conv (SAME) +
// cls passthrough -> locb (B,1025,512) bf16, no RMW (added in k_flash).
__global__ __launch_bounds__(256) void k_prep(const float* __restrict__ x,
                                              const float* __restrict__ wqkv,
                                              const float* __restrict__ wout,
                                              bf16* __restrict__ xb, bf16* __restrict__ wqkvb,
                                              bf16* __restrict__ woutb,
                                              const float* __restrict__ wdw,
                                              bf16* __restrict__ locb) {
  if (blockIdx.x >= 5696) {
    const int lb = blockIdx.x - 5696;          // 0..2047
    const int b = lb >> 8;
    const int y = (lb >> 3) & 31;
    const int xseg = lb & 7;
    const int c = threadIdx.x * 2;
    const int x0 = xseg * 4;
    const bool hm = (y > 0), hp = (y < 31);
    float wa[9], wb[9];
#pragma unroll
    for (int k = 0; k < 9; ++k) {
      wa[k] = wdw[(size_t)c * 9 + k];
      wb[k] = wdw[(size_t)(c + 1) * 9 + k];
    }
    const float* xrow = x + ((size_t)b * 1025 + 1) * 512 + c;
    float A0 = 0.f, B0 = 0.f, A1 = 0.f, B1 = 0.f;
    for (int cc = x0 - 1; cc <= x0 + 4; ++cc) {
      float2 v0 = make_float2(0.f, 0.f), v1 = v0, v2 = v0;
      if (cc >= 0 && cc < 32) {
        v1 = *(const float2*)&xrow[((size_t)y * 32 + cc) * 512];
        if (hm) v0 = *(const float2*)&xrow[((size_t)(y - 1) * 32 + cc) * 512];
        if (hp) v2 = *(const float2*)&xrow[((size_t)(y + 1) * 32 + cc) * 512];
      }
      float t0a = v0.x * wa[0] + v1.x * wa[3] + v2.x * wa[6];
      float t1a = v0.x * wa[1] + v1.x * wa[4] + v2.x * wa[7];
      float t2a = v0.x * wa[2] + v1.x * wa[5] + v2.x * wa[8];
      float t0b = v0.y * wb[0] + v1.y * wb[3] + v2.y * wb[6];
      float t1b = v0.y * wb[1] + v1.y * wb[4] + v2.y * wb[7];
      float t2b = v0.y * wb[2] + v1.y * wb[5] + v2.y * wb[8];
      int oc = cc - 1;
      if (oc >= x0 && oc <= x0 + 3) {
        size_t o = ((size_t)b * 1025 + 1 + y * 32 + oc) * 512 + c;
        *(uint32_t*)&locb[o] = pk2(A0 + t2a, A1 + t2b);
      }
      A0 = B0 + t1a; B0 = t0a;
      A1 = B1 + t1b; B1 = t0b;
    }
    if (y == 0 && xseg == 0) {
      float2 xc = *(const float2*)&x[((size_t)b * 1025) * 512 + c];
      *(uint32_t*)&locb[((size_t)b * 1025) * 512 + c] = pk2(xc.x, xc.y);
    }
    return;
  }
  int i = blockIdx.x * 256 + threadIdx.x;
  const float* src = nullptr;
  bf16* dst = nullptr;
  int q = i;
  bool zero = false;
  if (i < 1064960) {
    if (i < 1049600) src = x; else zero = true;
    dst = xb;
  } else if (i < 1064960 + 294912) {
    q = i - 1064960; src = wqkv; dst = wqkvb;
  } else {
    q = i - (1064960 + 294912); src = wout; dst = woutb;
  }
  float4 v = make_float4(0.f, 0.f, 0.f, 0.f);
  if (!zero) v = *(const float4*)&src[(size_t)q * 4];
  uint2 p;
  p.x = pk2(v.x, v.y);
  p.y = pk2(v.z, v.w);
  *(uint2*)&dst[(size_t)q * 4] = p;
}

// Tiled bf16 GEMM, 3-STAGE pipeline (T3+T4): BK=32, triple-buffered LDS,
// counted vmcnt (next stage's LOADS stay in flight) -> prefetch distance 2.
// Chunk swizzle (row>>1)&3. Bijective XCD-chunked 1D grid (m204).
// SWAPPED-OPERAND epilogue: reg r = 4 consecutive CHANNELS, lane l15 = M-row.
// EPI=0 (64x128, NTN=18): scatter q/k (q pre-scaled), V into vP. Grid 2340.
// EPI=1 (64x64, NTN=8): +bias, fp32 out, row<8200. Grid 1040.
template <int EPI, int BM, int BN, int NTN>
__global__ __launch_bounds__(256) void k_gemm(const bf16* __restrict__ A,
                                              const bf16* __restrict__ Bt, int K,
                                              bf16* __restrict__ q, bf16* __restrict__ kk,
                                              bf16* __restrict__ vt,
                                              const float* __restrict__ bias,
                                              float* __restrict__ out) {
  __shared__ __attribute__((aligned(16))) bf16 sA[3][BM * 32];
  __shared__ __attribute__((aligned(16))) bf16 sB[3][BN * 32];
  constexpr int WROWS = BM / 2, WCOLS = BN / 2;
  constexpr int MF = WROWS / 16, NF = WCOLS / 16;
  constexpr int LOADS = BM / 64 + BN / 64;  // gload_lds16 per wave per stage
  const int tid = threadIdx.x;
  const int lane = tid & 63;
  const int w = tid >> 6;
  const int wr = w >> 1, wc = w & 1;
  const int l15 = lane & 15, l4 = lane >> 4;

  const int nwg = gridDim.x;
  const int qq = nwg >> 3, rr = nwg & 7;
  const int xcd = blockIdx.x & 7, idx = blockIdx.x >> 3;
  const int logical = (xcd < rr) ? xcd * (qq + 1) + idx
                                 : rr * (qq + 1) + (xcd - rr) * qq + idx;
  const int tm = logical / NTN, tn = logical - tm * NTN;

  f32x4 acc[MF][NF] = {};

  const int srow = lane >> 2, schunk = lane & 3;
  const int rA = w * (BM / 4) + srow;
  const bf16* aS = A + ((size_t)(tm * BM + rA)) * K + ((schunk ^ ((rA >> 1) & 3)) * 8);
  const int rB = w * (BN / 4) + srow;
  const bf16* bS = Bt + ((size_t)(tn * BN + rB)) * K + ((schunk ^ ((rB >> 1) & 3)) * 8);

  auto STAGE = [&](int bi, int kt) {
    size_t o = (size_t)kt * 32;
#pragma unroll
    for (int i = 0; i < BM / 64; ++i)
      gload_lds16(aS + (size_t)i * 16 * K + o, &sA[bi][(w * (BM / 4) + i * 16) * 32]);
#pragma unroll
    for (int i = 0; i < BN / 64; ++i)
      gload_lds16(bS + (size_t)i * 16 * K + o, &sB[bi][(w * (BN / 4) + i * 16) * 32]);
  };

  STAGE(0, 0);
  STAGE(1, 1);
  int cur = 0;
  const int Ksteps = K >> 5;
  for (int kt = 0; kt < Ksteps; ++kt) {
    if (kt + 1 < Ksteps) {
      if constexpr (LOADS == 4)      asm volatile("s_waitcnt vmcnt(4)" ::: "memory");
      else if constexpr (LOADS == 3) asm volatile("s_waitcnt vmcnt(3)" ::: "memory");
      else                           asm volatile("s_waitcnt vmcnt(2)" ::: "memory");
    } else {
      asm volatile("s_waitcnt vmcnt(0)" ::: "memory");
    }
    __builtin_amdgcn_s_barrier();
    __builtin_amdgcn_sched_barrier(0);
    if (kt + 2 < Ksteps) {
      int b2 = cur + 2; if (b2 >= 3) b2 -= 3;
      STAGE(b2, kt + 2);
    }

    const bf16* a_ = sA[cur];
    const bf16* b_ = sB[cur];
    bf16x8 af[MF], bfr[NF];
#pragma unroll
    for (int mf = 0; mf < MF; ++mf) {
      int row = wr * WROWS + mf * 16 + l15;
      int phys = l4 ^ ((row >> 1) & 3);
      af[mf] = *(const bf16x8*)&a_[row * 32 + phys * 8];
    }
#pragma unroll
    for (int nf = 0; nf < NF; ++nf) {
      int row = wc * WCOLS + nf * 16 + l15;
      int phys = l4 ^ ((row >> 1) & 3);
      bfr[nf] = *(const bf16x8*)&b_[row * 32 + phys * 8];
    }
    __builtin_amdgcn_s_setprio(1);
#pragma unroll
    for (int mf = 0; mf < MF; ++mf)
#pragma unroll
      for (int nf = 0; nf < NF; ++nf)
        acc[mf][nf] =
            __builtin_amdgcn_mfma_f32_16x16x32_bf16(bfr[nf], af[mf], acc[mf][nf], 0, 0, 0);
    __builtin_amdgcn_s_setprio(0);
    ++cur; if (cur >= 3) cur = 0;
  }

  const int RbaseL = tm * BM + wr * WROWS + l15;
  const int CbaseL = tn * BN + wc * WCOLS + l4 * 4;
#pragma unroll
  for (int mf = 0; mf < MF; ++mf) {
    int R = RbaseL + mf * 16;
    if (R >= 8200) continue;
    if (EPI == 0) {
      int b = R / 1025;
      int n = R - b * 1025;
      int kvq = n >> 2, e = n & 3;
#pragma unroll
      for (int nf = 0; nf < NF; ++nf) {
        int Cc0 = CbaseL + nf * 16;                 // 4-aligned; 4 vals same seg
        int seg = (Cc0 >= 1536) ? 2 : (Cc0 >= 768 ? 1 : 0);
        int inner = Cc0 - seg * 768;
        int h = inner >> 6, d0 = inner & 63;        // d0..d0+3 within same head
        if (seg == 2) {
          bf16* vb = &vt[(((size_t)(b * 12 + h) * 272 + kvq) * 64 + d0) * 4 + e];
#pragma unroll
          for (int r = 0; r < 4; ++r) vb[r * 4] = (bf16)acc[mf][nf][r];
        } else {
          bf16* dst = seg ? kk : q;
          float scl = seg ? 1.f : QSCALE;
          uint2 p;
          p.x = pk2(acc[mf][nf][0] * scl, acc[mf][nf][1] * scl);
          p.y = pk2(acc[mf][nf][2] * scl, acc[mf][nf][3] * scl);
          *(uint2*)&dst[(((size_t)b * 12 + h) * 1088 + n) * 64 + d0] = p;
        }
      }
    } else {
#pragma unroll
      for (int nf = 0; nf < NF; ++nf) {
        int Cc0 = CbaseL + nf * 16;
        float4 bz = *(const float4*)&bias[Cc0];
        float4 o4;
        o4.x = acc[mf][nf][0] + bz.x;
        o4.y = acc[mf][nf][1] + bz.y;
        o4.z = acc[mf][nf][2] + bz.z;
        o4.w = acc[mf][nf][3] + bz.w;
        *(float4*)&out[(size_t)R * 512 + Cc0] = o4;
      }
    }
  }
}

// Flash attention, swapped-QK^T, shift-free softmax, rank-1 tail.
// K double-buffered (16 KB), V SINGLE-buffered (8 KB): V(t) staged at top of
// iter t (post-barrier -> PV(t-1) done everywhere -> overwrite race-free),
// consumed after a 2nd counted-wait barrier (vmcnt(2): K(t+1) stays in
// flight) placed after QK^T+softmax (~400cy) which hides the V load latency.
// LDS 24576 -> 6 blocks/CU (capacity 1536 vs grid 1632; was 1280 = 22% tail).
// NOTE: do NOT add a min-waves launch_bounds here — (256,4) capped VGPRs and
// caused 250 MB of scratch spill (round 4: 77us -> 151us).
__global__ __launch_bounds__(256) void k_flash(const bf16* __restrict__ qg,
                                               const bf16* __restrict__ kg,
                                               const bf16* __restrict__ vpg,
                                               const bf16* __restrict__ locb,
                                               bf16* __restrict__ outb) {
  __shared__ __attribute__((aligned(16))) bf16 sK[2][64 * 64];
  __shared__ __attribute__((aligned(16))) bf16 sVP[16 * 256];  // 16 kvq x 64 d x 4 e
  const int tid = threadIdx.x, lane = tid & 63, w = tid >> 6;
  const int l15 = lane & 15, l4 = lane >> 4;
  const int wg = blockIdx.x;
  const int logical = (wg & 7) * 204 + (wg >> 3);
  const int bh = logical / 17, qgp = logical - bh * 17;
  const int b = bh / 12, h = bh - b * 12;
  const int srow = lane >> 3, sslot = lane & 7;

  size_t qoff = ((size_t)bh * 1088 + qgp * 64 + w * 16 + l15) * 64 + l4 * 8;
  const bf16x8 qf0 = *(const bf16x8*)&qg[qoff];
  const bf16x8 qf1 = *(const bf16x8*)&qg[qoff + 32];

  float lreg = 0.f;  // per-lane partial row sum (reduced in epilogue)
  f32x4 oa[4] = {};

  const int px0 = (l4 ^ (l15 & 7)) * 8;
  const int px1 = ((4 + l4) ^ (l15 & 7)) * 8;

  const int rowA = w * 16 + srow, rowB = rowA + 8;
  const int clogA = sslot ^ (rowA & 7), clogB = sslot ^ (rowB & 7);
  const bf16* kS1 = kg + ((size_t)bh * 1088 + rowA) * 64 + clogA * 8;
  const bf16* kS2 = kg + ((size_t)bh * 1088 + rowB) * 64 + clogB * 8;
  const bf16* vS1 = vpg + (size_t)bh * 69632 + w * 1024 + lane * 8;
  const bf16* vS2 = vS1 + 512;
  const int kD1 = rowA * 64, kD2 = rowB * 64;
  const int vD1 = w * 1024 + lane * 8, vD2 = vD1 + 512;

  auto ST_K = [&](int bi, int t) {
    size_t o = (size_t)t * 4096;
    gload_lds16(kS1 + o, &sK[bi][kD1]);
    gload_lds16(kS2 + o, &sK[bi][kD2]);
  };
  auto ST_V = [&](int t) {
    size_t o = (size_t)t * 4096;
    gload_lds16(vS1 + o, &sVP[vD1]);
    gload_lds16(vS2 + o, &sVP[vD2]);
  };

  ST_K(0, 0);
  int cur = 0;

  for (int t = 0; t < 16; ++t) {
    // Wait K(t) (issued one full iteration ago); converge. All waves are past
    // PV(t-1) here, so overwriting the single V buffer below is race-free.
    asm volatile("s_waitcnt vmcnt(0)" ::: "memory");
    __builtin_amdgcn_s_barrier();
    __builtin_amdgcn_sched_barrier(0);
    ST_V(t);                       // V for THIS tile (consumed after barrier 2)
    if (t < 15) ST_K(cur ^ 1, t + 1);

    const bf16* kb_ = sK[cur];

    f32x4 sc[4] = {};
    __builtin_amdgcn_s_setprio(1);
#pragma unroll
    for (int jt = 0; jt < 4; ++jt) {
      bf16x8 a0 = *(const bf16x8*)&kb_[(jt * 16 + l15) * 64 + px0];
      sc[jt] = __builtin_amdgcn_mfma_f32_16x16x32_bf16(a0, qf0, sc[jt], 0, 0, 0);
    }
#pragma unroll
    for (int jt = 0; jt < 4; ++jt) {
      bf16x8 a1 = *(const bf16x8*)&kb_[(jt * 16 + l15) * 64 + px1];
      sc[jt] = __builtin_amdgcn_mfma_f32_16x16x32_bf16(a1, qf1, sc[jt], 0, 0, 0);
    }
    __builtin_amdgcn_s_setprio(0);

    union { uint32_t u[2]; s4 v; } pa[4];
    float lsum = 0.f;
#pragma unroll
    for (int jt = 0; jt < 4; ++jt) {
      float p0 = fexp2(sc[jt][0]);
      float p1 = fexp2(sc[jt][1]);
      float p2 = fexp2(sc[jt][2]);
      float p3 = fexp2(sc[jt][3]);
      lsum += (p0 + p1) + (p2 + p3);
      pa[jt].u[0] = pk2(p0, p1);
      pa[jt].u[1] = pk2(p2, p3);
    }
    lreg += lsum;

    // Barrier 2: V(t) resident (vmcnt(2) leaves only K(t+1) in flight; last
    // iter has no K prefetch -> vmcnt(0)).
    if (t < 15) asm volatile("s_waitcnt vmcnt(2)" ::: "memory");
    else        asm volatile("s_waitcnt vmcnt(0)" ::: "memory");
    __builtin_amdgcn_s_barrier();
    __builtin_amdgcn_sched_barrier(0);

    __builtin_amdgcn_s_setprio(1);
#pragma unroll
    for (int jt = 0; jt < 4; ++jt)
#pragma unroll
      for (int db = 0; db < 4; ++db) {
        s4 vf = *(const s4*)&sVP[((jt * 4 + l4) * 64 + db * 16 + l15) * 4];
        oa[db] = pv_mfma(pa[jt].v, vf, oa[db]);
      }
    __builtin_amdgcn_s_setprio(0);
    cur ^= 1;
  }

  // Rank-1 tail: kv = 1024.
  {
    const bf16* k1 = kg + ((size_t)bh * 1088 + 1024) * 64;
    bf16x8 kA = *(const bf16x8*)&k1[l4 * 8];
    bf16x8 kB = *(const bf16x8*)&k1[32 + l4 * 8];
    float s = 0.f;
#pragma unroll
    for (int e = 0; e < 8; ++e)
      s += (float)qf0[e] * (float)kA[e] + (float)qf1[e] * (float)kB[e];
    s += __shfl_xor(s, 16);
    s += __shfl_xor(s, 32);
    float p = fexp2(s);
    if (l4 == 0) lreg += p;  // count once per q-row (epilogue sums l4 copies)
    float pr[4];
#pragma unroll
    for (int r = 0; r < 4; ++r) pr[r] = __shfl(p, l4 * 4 + r);
    const bf16* v1 = vpg + (size_t)bh * 69632 + 65536;  // kvq=256, e=0
#pragma unroll
    for (int db = 0; db < 4; ++db) {
      float vd = (float)v1[(db * 16 + l15) * 4];
#pragma unroll
      for (int r = 0; r < 4; ++r) oa[db][r] += pr[r] * vd;
    }
  }

  float ls = lreg;
  ls += __shfl_xor(ls, 16);
  ls += __shfl_xor(ls, 32);
  float linv = frcp(ls);
#pragma unroll
  for (int r = 0; r < 4; ++r) {
    float ir = __shfl(linv, l4 * 4 + r);
    int n = qgp * 64 + w * 16 + l4 * 4 + r;
    if (n >= 1025) continue;
#pragma unroll
    for (int db = 0; db < 4; ++db) {
      float v = oa[db][r] * ir;
      if (h < 8)
        v += (float)locb[((size_t)b * 1025 + n) * 512 + h * 64 + db * 16 + l15];
      outb[((size_t)b * 1025 + n) * 768 + h * 64 + db * 16 + l15] = (bf16)v;
    }
  }
}

extern "C" void kernel_launch(void* const* d_in, const int* in_sizes, int n_in,
                              void* d_out, int out_size, void* d_ws, size_t ws_size,
                              hipStream_t stream) {
  const float* x = (const float*)d_in[0];
  const float* w_qkv = (const float*)d_in[1];
  const float* w_dw = (const float*)d_in[2];
  const float* w_out = (const float*)d_in[3];
  const float* b_out = (const float*)d_in[4];
  float* out = (float*)d_out;

  char* ws = (char*)d_ws;
  size_t off = 0;
  auto alloc = [&](size_t bytes) {
    char* p = ws + off;
    off = (off + bytes + 255) & ~(size_t)255;
    return p;
  };
  bf16* xb    = (bf16*)alloc((size_t)8320 * 512 * 2);
  bf16* wqkvb = (bf16*)alloc((size_t)2304 * 512 * 2);
  bf16* woutb = (bf16*)alloc((size_t)512 * 768 * 2);
  bf16* qb    = (bf16*)alloc((size_t)96 * 1088 * 64 * 2);
  bf16* kb    = (bf16*)alloc((size_t)96 * 1088 * 64 * 2);
  bf16* vP    = (bf16*)alloc((size_t)96 * 272 * 64 * 4 * 2);  // 69632 elems/head
  bf16* locb  = (bf16*)alloc((size_t)8 * 1025 * 512 * 2);
  bf16* outb  = (bf16*)alloc((size_t)8320 * 768 * 2);

  // Fused prep + conv: 5696 prep blocks + 2048 conv blocks
  k_prep<<<7744, 256, 0, stream>>>(x, w_qkv, w_out, xb, wqkvb, woutb, w_dw, locb);
  // 2340 = 130*18 blocks (64x128 tiles), XCD-chunked inside the kernel
  k_gemm<0, 64, 128, 18><<<2340, 256, 0, stream>>>(xb, wqkvb, 512, qb, kb, vP,
                                                   nullptr, nullptr);
  k_flash<<<1632, 256, 0, stream>>>(qb, kb, vP, locb, outb);
  // 1040 = 130*8 blocks
  k_gemm<1, 64, 64, 8><<<1040, 256, 0, stream>>>(outb, woutb, 768, nullptr, nullptr,
                                                 nullptr, b_out, out);
}

// Round 20
// 134.135 us; speedup vs baseline: 1.0151x; 1.0122x over previous
//
#include <hip/hip_runtime.h>
#include <hip/hip_bf16.h>
#include <stdint.h>
#include <math.h>

typedef __bf16 bf16;
typedef __bf16 bf16x8 __attribute__((ext_vector_type(8)));
typedef float f32x4 __attribute__((ext_vector_type(4)));
typedef short s4 __attribute__((ext_vector_type(4)));  // 4 bf16 (2 VGPR)

#define QSCALE 0.1803368801111f  /* 0.125 * log2(e) */

// B=8, N=1025 (32*32+1), DIM=512, HEADS=12, DH=64, INNER=768
// M = 8*1025 = 8200, padded to 8320. KV per (b,h): 1025 = 16*64 + 1 -> 16 full
// tiles + rank-1 tail (kv=1024) handled in-register.
// V layout "vP": per head [kvq=272][d=64][e=4], kv = kvq*4+e.
// PV uses mfma_f32_16x16x16_bf16 whose A-fragment (lane: A[l15][4*l4+e])
// exactly matches the swapped-QK^T P ownership; no cross-lane P movement.
// Softmax: shift-free (scores exp2-domain max ~8.3 -> p<=~300, FP-safe).
// ROUND-16 LESSON: V fragments must come from LDS. ROUND-18 LESSON: ones-MFMA
// denominator costs more matrix-pipe than the VALU it saves. ROUND-19 LESSON:
// occupancy was WAVE-limited (4-wave blocks -> 24/32 waves/CU), not LDS-
// limited. This round: 8-wave blocks (512 thr), 128 q-rows, grid 864 -> 4
// blocks/CU x 8 waves = 32 waves/CU, single dispatch round, half the
// barriers+staging per q-row.

__device__ __forceinline__ void gload_lds16(const void* g, void* l) {
  typedef const __attribute__((address_space(1))) char g_char;
  typedef __attribute__((address_space(3))) char l_char;
  g_char* gp = (g_char*)(uintptr_t)g;
  l_char* lp = (l_char*)(uint32_t)(uintptr_t)l;
  __builtin_amdgcn_global_load_lds(gp, lp, 16, 0, 0);
}

__device__ __forceinline__ float fexp2(float x) {
#if __has_builtin(__builtin_amdgcn_exp2f)
  return __builtin_amdgcn_exp2f(x);
#else
  return exp2f(x);
#endif
}

__device__ __forceinline__ float frcp(float x) {
#if __has_builtin(__builtin_amdgcn_rcpf)
  return __builtin_amdgcn_rcpf(x);
#else
  return 1.f / x;
#endif
}

__device__ __forceinline__ uint32_t pk2(float a, float b) {
  union { bf16 h; unsigned short u; } ua, ub;
  ua.h = (bf16)a; ub.h = (bf16)b;
  return (uint32_t)ua.u | ((uint32_t)ub.u << 16);
}

__device__ __forceinline__ f32x4 pv_mfma(s4 a, s4 b, f32x4 c) {
#if __has_builtin(__builtin_amdgcn_mfma_f32_16x16x16bf16_1k)
  return __builtin_amdgcn_mfma_f32_16x16x16bf16_1k(a, b, c, 0, 0, 0);
#else
  asm volatile("v_mfma_f32_16x16x16_bf16 %0, %1, %2, %0" : "+v"(c) : "v"(a), "v"(b));
  return c;
#endif
}

// FUSED prep + depthwise conv. Blocks [0,5696): x->xb (pad to 8320 rows),
// w_qkv->bf16, w_out->bf16. Blocks [5696,7744): 3x3 depthwise conv (SAME) +
// cls passthrough -> locb (B,1025,512) bf16, no RMW (added in k_flash).
__global__ __launch_bounds__(256) void k_prep(const float* __restrict__ x,
                                              const float* __restrict__ wqkv,
                                              const float* __restrict__ wout,
                                              bf16* __restrict__ xb, bf16* __restrict__ wqkvb,
                                              bf16* __restrict__ woutb,
                                              const float* __restrict__ wdw,
                                              bf16* __restrict__ locb) {
  if (blockIdx.x >= 5696) {
    const int lb = blockIdx.x - 5696;          // 0..2047
    const int b = lb >> 8;
    const int y = (lb >> 3) & 31;
    const int xseg = lb & 7;
    const int c = threadIdx.x * 2;
    const int x0 = xseg * 4;
    const bool hm = (y > 0), hp = (y < 31);
    float wa[9], wb[9];
#pragma unroll
    for (int k = 0; k < 9; ++k) {
      wa[k] = wdw[(size_t)c * 9 + k];
      wb[k] = wdw[(size_t)(c + 1) * 9 + k];
    }
    const float* xrow = x + ((size_t)b * 1025 + 1) * 512 + c;
    float A0 = 0.f, B0 = 0.f, A1 = 0.f, B1 = 0.f;
    for (int cc = x0 - 1; cc <= x0 + 4; ++cc) {
      float2 v0 = make_float2(0.f, 0.f), v1 = v0, v2 = v0;
      if (cc >= 0 && cc < 32) {
        v1 = *(const float2*)&xrow[((size_t)y * 32 + cc) * 512];
        if (hm) v0 = *(const float2*)&xrow[((size_t)(y - 1) * 32 + cc) * 512];
        if (hp) v2 = *(const float2*)&xrow[((size_t)(y + 1) * 32 + cc) * 512];
      }
      float t0a = v0.x * wa[0] + v1.x * wa[3] + v2.x * wa[6];
      float t1a = v0.x * wa[1] + v1.x * wa[4] + v2.x * wa[7];
      float t2a = v0.x * wa[2] + v1.x * wa[5] + v2.x * wa[8];
      float t0b = v0.y * wb[0] + v1.y * wb[3] + v2.y * wb[6];
      float t1b = v0.y * wb[1] + v1.y * wb[4] + v2.y * wb[7];
      float t2b = v0.y * wb[2] + v1.y * wb[5] + v2.y * wb[8];
      int oc = cc - 1;
      if (oc >= x0 && oc <= x0 + 3) {
        size_t o = ((size_t)b * 1025 + 1 + y * 32 + oc) * 512 + c;
        *(uint32_t*)&locb[o] = pk2(A0 + t2a, A1 + t2b);
      }
      A0 = B0 + t1a; B0 = t0a;
      A1 = B1 + t1b; B1 = t0b;
    }
    if (y == 0 && xseg == 0) {
      float2 xc = *(const float2*)&x[((size_t)b * 1025) * 512 + c];
      *(uint32_t*)&locb[((size_t)b * 1025) * 512 + c] = pk2(xc.x, xc.y);
    }
    return;
  }
  int i = blockIdx.x * 256 + threadIdx.x;
  const float* src = nullptr;
  bf16* dst = nullptr;
  int q = i;
  bool zero = false;
  if (i < 1064960) {
    if (i < 1049600) src = x; else zero = true;
    dst = xb;
  } else if (i < 1064960 + 294912) {
    q = i - 1064960; src = wqkv; dst = wqkvb;
  } else {
    q = i - (1064960 + 294912); src = wout; dst = woutb;
  }
  float4 v = make_float4(0.f, 0.f, 0.f, 0.f);
  if (!zero) v = *(const float4*)&src[(size_t)q * 4];
  uint2 p;
  p.x = pk2(v.x, v.y);
  p.y = pk2(v.z, v.w);
  *(uint2*)&dst[(size_t)q * 4] = p;
}

// Tiled bf16 GEMM, 3-STAGE pipeline (T3+T4): BK=32, triple-buffered LDS,
// counted vmcnt (next stage's LOADS stay in flight) -> prefetch distance 2.
// Chunk swizzle (row>>1)&3. Bijective XCD-chunked 1D grid (m204).
// SWAPPED-OPERAND epilogue: reg r = 4 consecutive CHANNELS, lane l15 = M-row.
// EPI=0 (64x128, NTN=18): scatter q/k (q pre-scaled), V into vP. Grid 2340.
// EPI=1 (64x64, NTN=8): +bias, fp32 out, row<8200. Grid 1040.
template <int EPI, int BM, int BN, int NTN>
__global__ __launch_bounds__(256) void k_gemm(const bf16* __restrict__ A,
                                              const bf16* __restrict__ Bt, int K,
                                              bf16* __restrict__ q, bf16* __restrict__ kk,
                                              bf16* __restrict__ vt,
                                              const float* __restrict__ bias,
                                              float* __restrict__ out) {
  __shared__ __attribute__((aligned(16))) bf16 sA[3][BM * 32];
  __shared__ __attribute__((aligned(16))) bf16 sB[3][BN * 32];
  constexpr int WROWS = BM / 2, WCOLS = BN / 2;
  constexpr int MF = WROWS / 16, NF = WCOLS / 16;
  constexpr int LOADS = BM / 64 + BN / 64;  // gload_lds16 per wave per stage
  const int tid = threadIdx.x;
  const int lane = tid & 63;
  const int w = tid >> 6;
  const int wr = w >> 1, wc = w & 1;
  const int l15 = lane & 15, l4 = lane >> 4;

  const int nwg = gridDim.x;
  const int qq = nwg >> 3, rr = nwg & 7;
  const int xcd = blockIdx.x & 7, idx = blockIdx.x >> 3;
  const int logical = (xcd < rr) ? xcd * (qq + 1) + idx
                                 : rr * (qq + 1) + (xcd - rr) * qq + idx;
  const int tm = logical / NTN, tn = logical - tm * NTN;

  f32x4 acc[MF][NF] = {};

  const int srow = lane >> 2, schunk = lane & 3;
  const int rA = w * (BM / 4) + srow;
  const bf16* aS = A + ((size_t)(tm * BM + rA)) * K + ((schunk ^ ((rA >> 1) & 3)) * 8);
  const int rB = w * (BN / 4) + srow;
  const bf16* bS = Bt + ((size_t)(tn * BN + rB)) * K + ((schunk ^ ((rB >> 1) & 3)) * 8);

  auto STAGE = [&](int bi, int kt) {
    size_t o = (size_t)kt * 32;
#pragma unroll
    for (int i = 0; i < BM / 64; ++i)
      gload_lds16(aS + (size_t)i * 16 * K + o, &sA[bi][(w * (BM / 4) + i * 16) * 32]);
#pragma unroll
    for (int i = 0; i < BN / 64; ++i)
      gload_lds16(bS + (size_t)i * 16 * K + o, &sB[bi][(w * (BN / 4) + i * 16) * 32]);
  };

  STAGE(0, 0);
  STAGE(1, 1);
  int cur = 0;
  const int Ksteps = K >> 5;
  for (int kt = 0; kt < Ksteps; ++kt) {
    if (kt + 1 < Ksteps) {
      if constexpr (LOADS == 4)      asm volatile("s_waitcnt vmcnt(4)" ::: "memory");
      else if constexpr (LOADS == 3) asm volatile("s_waitcnt vmcnt(3)" ::: "memory");
      else                           asm volatile("s_waitcnt vmcnt(2)" ::: "memory");
    } else {
      asm volatile("s_waitcnt vmcnt(0)" ::: "memory");
    }
    __builtin_amdgcn_s_barrier();
    __builtin_amdgcn_sched_barrier(0);
    if (kt + 2 < Ksteps) {
      int b2 = cur + 2; if (b2 >= 3) b2 -= 3;
      STAGE(b2, kt + 2);
    }

    const bf16* a_ = sA[cur];
    const bf16* b_ = sB[cur];
    bf16x8 af[MF], bfr[NF];
#pragma unroll
    for (int mf = 0; mf < MF; ++mf) {
      int row = wr * WROWS + mf * 16 + l15;
      int phys = l4 ^ ((row >> 1) & 3);
      af[mf] = *(const bf16x8*)&a_[row * 32 + phys * 8];
    }
#pragma unroll
    for (int nf = 0; nf < NF; ++nf) {
      int row = wc * WCOLS + nf * 16 + l15;
      int phys = l4 ^ ((row >> 1) & 3);
      bfr[nf] = *(const bf16x8*)&b_[row * 32 + phys * 8];
    }
    __builtin_amdgcn_s_setprio(1);
#pragma unroll
    for (int mf = 0; mf < MF; ++mf)
#pragma unroll
      for (int nf = 0; nf < NF; ++nf)
        acc[mf][nf] =
            __builtin_amdgcn_mfma_f32_16x16x32_bf16(bfr[nf], af[mf], acc[mf][nf], 0, 0, 0);
    __builtin_amdgcn_s_setprio(0);
    ++cur; if (cur >= 3) cur = 0;
  }

  const int RbaseL = tm * BM + wr * WROWS + l15;
  const int CbaseL = tn * BN + wc * WCOLS + l4 * 4;
#pragma unroll
  for (int mf = 0; mf < MF; ++mf) {
    int R = RbaseL + mf * 16;
    if (R >= 8200) continue;
    if (EPI == 0) {
      int b = R / 1025;
      int n = R - b * 1025;
      int kvq = n >> 2, e = n & 3;
#pragma unroll
      for (int nf = 0; nf < NF; ++nf) {
        int Cc0 = CbaseL + nf * 16;                 // 4-aligned; 4 vals same seg
        int seg = (Cc0 >= 1536) ? 2 : (Cc0 >= 768 ? 1 : 0);
        int inner = Cc0 - seg * 768;
        int h = inner >> 6, d0 = inner & 63;        // d0..d0+3 within same head
        if (seg == 2) {
          bf16* vb = &vt[(((size_t)(b * 12 + h) * 272 + kvq) * 64 + d0) * 4 + e];
#pragma unroll
          for (int r = 0; r < 4; ++r) vb[r * 4] = (bf16)acc[mf][nf][r];
        } else {
          bf16* dst = seg ? kk : q;
          float scl = seg ? 1.f : QSCALE;
          uint2 p;
          p.x = pk2(acc[mf][nf][0] * scl, acc[mf][nf][1] * scl);
          p.y = pk2(acc[mf][nf][2] * scl, acc[mf][nf][3] * scl);
          *(uint2*)&dst[(((size_t)b * 12 + h) * 1088 + n) * 64 + d0] = p;
        }
      }
    } else {
#pragma unroll
      for (int nf = 0; nf < NF; ++nf) {
        int Cc0 = CbaseL + nf * 16;
        float4 bz = *(const float4*)&bias[Cc0];
        float4 o4;
        o4.x = acc[mf][nf][0] + bz.x;
        o4.y = acc[mf][nf][1] + bz.y;
        o4.z = acc[mf][nf][2] + bz.z;
        o4.w = acc[mf][nf][3] + bz.w;
        *(float4*)&out[(size_t)R * 512 + Cc0] = o4;
      }
    }
  }
}

// Flash attention, swapped-QK^T, double-buffered K/V, shift-free softmax.
// 8 WAVES per block (512 thr), 128 q-rows/block, grid 864 (= 8*108, exact
// XCD-bijective): 4 blocks/CU x 8 waves = 32 waves/CU (100% wave occupancy,
// vs 4-wave blocks' 24 cap) and a single dispatch round (864 <= 1024).
// Staging amortized: each wave issues 1 K + 1 V gload_lds16 per tile.
// Group qgp=8 covers q-rows 1024..1151: only 1024 valid; garbage Q rows
// yield NaN confined to masked output lanes (same precedent as old qgp=16).
// 16 full KV tiles + rank-1 tail. PV via mfma_16x16x16 (P in-register).
// Epilogue fuses the depthwise-conv local branch: adds locb for heads h<8.
// LDS = 32768 B. NOTE: no min-waves launch_bounds (round-4 spill lesson).
__global__ __launch_bounds__(512) void k_flash(const bf16* __restrict__ qg,
                                               const bf16* __restrict__ kg,
                                               const bf16* __restrict__ vpg,
                                               const bf16* __restrict__ locb,
                                               bf16* __restrict__ outb) {
  __shared__ __attribute__((aligned(16))) bf16 sK[2][64 * 64];
  __shared__ __attribute__((aligned(16))) bf16 sVP[2][16 * 256];  // 16 kvq x 64 d x 4 e
  const int tid = threadIdx.x, lane = tid & 63, w = tid >> 6;  // w = 0..7
  const int l15 = lane & 15, l4 = lane >> 4;
  // XCD-contiguous mapping: 864 = 8 * 108
  const int wg = blockIdx.x;
  const int logical = (wg & 7) * 108 + (wg >> 3);
  const int bh = logical / 9, qgp = logical - bh * 9;   // 9 q-groups of 128
  const int b = bh / 12, h = bh - b * 12;

  // Q fragments (pre-scaled by QSCALE in the QKV GEMM epilogue)
  size_t qoff = ((size_t)bh * 1088 + qgp * 128 + w * 16 + l15) * 64 + l4 * 8;
  const bf16x8 qf0 = *(const bf16x8*)&qg[qoff];
  const bf16x8 qf1 = *(const bf16x8*)&qg[qoff + 32];

  float lreg = 0.f;  // per-lane partial row sum (reduced in epilogue)
  f32x4 oa[4] = {};

  const int px0 = (l4 ^ (l15 & 7)) * 8;        // K LDS swizzled chunk, ks=0
  const int px1 = ((4 + l4) ^ (l15 & 7)) * 8;  // ks=1

  // Staging: wave w covers K rows [w*8, w*8+8) (1 gload/wave) and V elements
  // [w*512, (w+1)*512) (1 gload/wave). Both tiles advance 4096 elems per t.
  const int rowK = w * 8 + (lane >> 3);
  const int clogK = (lane & 7) ^ (rowK & 7);
  const bf16* kS = kg + ((size_t)bh * 1088 + rowK) * 64 + clogK * 8;
  const bf16* vS = vpg + (size_t)bh * 69632 + w * 512 + lane * 8;
  const int kD = w * 512;   // wave-uniform LDS elem base (lane adds *8)
  const int vD = w * 512;

  auto STAGE = [&](int bi, int t) {
    size_t o = (size_t)t * 4096;
    gload_lds16(kS + o, &sK[bi][kD]);
    gload_lds16(vS + o, &sVP[bi][vD]);
  };

  STAGE(0, 0);
  int cur = 0;

  for (int t = 0; t < 16; ++t) {
    // Wait this tile's loads (issued one full iteration ago), converge. After
    // the barrier all waves consumed buf[cur^1] -> restage is race-free.
    asm volatile("s_waitcnt vmcnt(0)" ::: "memory");
    __builtin_amdgcn_s_barrier();
    __builtin_amdgcn_sched_barrier(0);
    if (t < 15) STAGE(cur ^ 1, t + 1);

    const bf16* kb_ = sK[cur];
    const bf16* vpb = sVP[cur];

    // S^T = K · Q^T : lane holds S[q=l15][kv = jt*16 + l4*4 + r]
    f32x4 sc[4] = {};
    __builtin_amdgcn_s_setprio(1);
#pragma unroll
    for (int jt = 0; jt < 4; ++jt) {
      bf16x8 a0 = *(const bf16x8*)&kb_[(jt * 16 + l15) * 64 + px0];
      sc[jt] = __builtin_amdgcn_mfma_f32_16x16x32_bf16(a0, qf0, sc[jt], 0, 0, 0);
    }
#pragma unroll
    for (int jt = 0; jt < 4; ++jt) {
      bf16x8 a1 = *(const bf16x8*)&kb_[(jt * 16 + l15) * 64 + px1];
      sc[jt] = __builtin_amdgcn_mfma_f32_16x16x32_bf16(a1, qf1, sc[jt], 0, 0, 0);
    }
    __builtin_amdgcn_s_setprio(0);

    // P = exp2(S); pack per-jt into the 16x16x16 A-fragment directly.
    union { uint32_t u[2]; s4 v; } pa[4];
    float lsum = 0.f;
#pragma unroll
    for (int jt = 0; jt < 4; ++jt) {
      float p0 = fexp2(sc[jt][0]);
      float p1 = fexp2(sc[jt][1]);
      float p2 = fexp2(sc[jt][2]);
      float p3 = fexp2(sc[jt][3]);
      lsum += (p0 + p1) + (p2 + p3);
      pa[jt].u[0] = pk2(p0, p1);
      pa[jt].u[1] = pk2(p2, p3);
    }
    lreg += lsum;

    // O += P · V  (16 x mfma_16x16x16, A = in-register P)
    __builtin_amdgcn_s_setprio(1);
#pragma unroll
    for (int jt = 0; jt < 4; ++jt)
#pragma unroll
      for (int db = 0; db < 4; ++db) {
        s4 vf = *(const s4*)&vpb[((jt * 4 + l4) * 64 + db * 16 + l15) * 4];
        oa[db] = pv_mfma(pa[jt].v, vf, oa[db]);
      }
    __builtin_amdgcn_s_setprio(0);
    cur ^= 1;
  }

  // Rank-1 tail: kv = 1024.
  {
    const bf16* k1 = kg + ((size_t)bh * 1088 + 1024) * 64;
    bf16x8 kA = *(const bf16x8*)&k1[l4 * 8];
    bf16x8 kB = *(const bf16x8*)&k1[32 + l4 * 8];
    float s = 0.f;
#pragma unroll
    for (int e = 0; e < 8; ++e)
      s += (float)qf0[e] * (float)kA[e] + (float)qf1[e] * (float)kB[e];
    s += __shfl_xor(s, 16);
    s += __shfl_xor(s, 32);
    float p = fexp2(s);
    if (l4 == 0) lreg += p;  // count once per q-row (epilogue sums l4 copies)
    float pr[4];
#pragma unroll
    for (int r = 0; r < 4; ++r) pr[r] = __shfl(p, l4 * 4 + r);
    const bf16* v1 = vpg + (size_t)bh * 69632 + 65536;  // kvq=256, e=0
#pragma unroll
    for (int db = 0; db < 4; ++db) {
      float vd = (float)v1[(db * 16 + l15) * 4];
#pragma unroll
      for (int r = 0; r < 4; ++r) oa[db][r] += pr[r] * vd;
    }
  }

  float ls = lreg;
  ls += __shfl_xor(ls, 16);
  ls += __shfl_xor(ls, 32);
  float linv = frcp(ls);
#pragma unroll
  for (int r = 0; r < 4; ++r) {
    float ir = __shfl(linv, l4 * 4 + r);
    int n = qgp * 128 + w * 16 + l4 * 4 + r;
    if (n >= 1025) continue;
#pragma unroll
    for (int db = 0; db < 4; ++db) {
      float v = oa[db][r] * ir;
      if (h < 8)
        v += (float)locb[((size_t)b * 1025 + n) * 512 + h * 64 + db * 16 + l15];
      outb[((size_t)b * 1025 + n) * 768 + h * 64 + db * 16 + l15] = (bf16)v;
    }
  }
}

extern "C" void kernel_launch(void* const* d_in, const int* in_sizes, int n_in,
                              void* d_out, int out_size, void* d_ws, size_t ws_size,
                              hipStream_t stream) {
  const float* x = (const float*)d_in[0];
  const float* w_qkv = (const float*)d_in[1];
  const float* w_dw = (const float*)d_in[2];
  const float* w_out = (const float*)d_in[3];
  const float* b_out = (const float*)d_in[4];
  float* out = (float*)d_out;

  char* ws = (char*)d_ws;
  size_t off = 0;
  auto alloc = [&](size_t bytes) {
    char* p = ws + off;
    off = (off + bytes + 255) & ~(size_t)255;
    return p;
  };
  bf16* xb    = (bf16*)alloc((size_t)8320 * 512 * 2);
  bf16* wqkvb = (bf16*)alloc((size_t)2304 * 512 * 2);
  bf16* woutb = (bf16*)alloc((size_t)512 * 768 * 2);
  bf16* qb    = (bf16*)alloc((size_t)96 * 1088 * 64 * 2);
  bf16* kb    = (bf16*)alloc((size_t)96 * 1088 * 64 * 2);
  bf16* vP    = (bf16*)alloc((size_t)96 * 272 * 64 * 4 * 2);  // 69632 elems/head
  bf16* locb  = (bf16*)alloc((size_t)8 * 1025 * 512 * 2);
  bf16* outb  = (bf16*)alloc((size_t)8320 * 768 * 2);

  // Fused prep + conv: 5696 prep blocks + 2048 conv blocks
  k_prep<<<7744, 256, 0, stream>>>(x, w_qkv, w_out, xb, wqkvb, woutb, w_dw, locb);
  // 2340 = 130*18 blocks (64x128 tiles), XCD-chunked inside the kernel
  k_gemm<0, 64, 128, 18><<<2340, 256, 0, stream>>>(xb, wqkvb, 512, qb, kb, vP,
                                                   nullptr, nullptr);
  k_flash<<<864, 512, 0, stream>>>(qb, kb, vP, locb, outb);
  // 1040 = 130*8 blocks
  k_gemm<1, 64, 64, 8><<<1040, 256, 0, stream>>>(outb, woutb, 768, nullptr, nullptr,
                                                 nullptr, b_out, out);
}

// Round 21
// 130.531 us; speedup vs baseline: 1.0432x; 1.0276x over previous
//
#include <hip/hip_runtime.h>
#include <hip/hip_bf16.h>
#include <stdint.h>
#include <math.h>

typedef __bf16 bf16;
typedef __bf16 bf16x8 __attribute__((ext_vector_type(8)));
typedef float f32x4 __attribute__((ext_vector_type(4)));
typedef short s4 __attribute__((ext_vector_type(4)));  // 4 bf16 (2 VGPR)

#define QSCALE 0.1803368801111f  /* 0.125 * log2(e) */

// B=8, N=1025 (32*32+1), DIM=512, HEADS=12, DH=64, INNER=768
// M = 8*1025 = 8200, padded to 8320. KV per (b,h): 1025 = 16*64 + 1 -> 16 full
// tiles + rank-1 tail (kv=1024) handled in-register.
// V layout "vP": per head [kvq=272][d=64][e=4], kv = kvq*4+e.
// PV uses mfma_f32_16x16x16_bf16 whose A-fragment (lane: A[l15][4*l4+e])
// exactly matches the swapped-QK^T P ownership; no cross-lane P movement.
// Softmax: shift-free (scores exp2-domain max ~8.3 -> p<=~300, FP-safe).
// ROUND-16: V must come from LDS. ROUND-18: ones-MFMA denominator loses.
// ROUND-19/20: occupancy was WAVE-limited; 8-wave flash blocks fixed it.
// ROUND-21: apply the same 8-wave rebuild to gemm0 (stuck ~54us across four
// 4-wave structures with MfmaUtil 13.6% / VALU 19.6% -> latency-bound).

__device__ __forceinline__ void gload_lds16(const void* g, void* l) {
  typedef const __attribute__((address_space(1))) char g_char;
  typedef __attribute__((address_space(3))) char l_char;
  g_char* gp = (g_char*)(uintptr_t)g;
  l_char* lp = (l_char*)(uint32_t)(uintptr_t)l;
  __builtin_amdgcn_global_load_lds(gp, lp, 16, 0, 0);
}

__device__ __forceinline__ float fexp2(float x) {
#if __has_builtin(__builtin_amdgcn_exp2f)
  return __builtin_amdgcn_exp2f(x);
#else
  return exp2f(x);
#endif
}

__device__ __forceinline__ float frcp(float x) {
#if __has_builtin(__builtin_amdgcn_rcpf)
  return __builtin_amdgcn_rcpf(x);
#else
  return 1.f / x;
#endif
}

__device__ __forceinline__ uint32_t pk2(float a, float b) {
  union { bf16 h; unsigned short u; } ua, ub;
  ua.h = (bf16)a; ub.h = (bf16)b;
  return (uint32_t)ua.u | ((uint32_t)ub.u << 16);
}

__device__ __forceinline__ f32x4 pv_mfma(s4 a, s4 b, f32x4 c) {
#if __has_builtin(__builtin_amdgcn_mfma_f32_16x16x16bf16_1k)
  return __builtin_amdgcn_mfma_f32_16x16x16bf16_1k(a, b, c, 0, 0, 0);
#else
  asm volatile("v_mfma_f32_16x16x16_bf16 %0, %1, %2, %0" : "+v"(c) : "v"(a), "v"(b));
  return c;
#endif
}

// FUSED prep + depthwise conv. Blocks [0,5696): x->xb (pad to 8320 rows),
// w_qkv->bf16, w_out->bf16. Blocks [5696,7744): 3x3 depthwise conv (SAME) +
// cls passthrough -> locb (B,1025,512) bf16, no RMW (added in k_flash).
__global__ __launch_bounds__(256) void k_prep(const float* __restrict__ x,
                                              const float* __restrict__ wqkv,
                                              const float* __restrict__ wout,
                                              bf16* __restrict__ xb, bf16* __restrict__ wqkvb,
                                              bf16* __restrict__ woutb,
                                              const float* __restrict__ wdw,
                                              bf16* __restrict__ locb) {
  if (blockIdx.x >= 5696) {
    const int lb = blockIdx.x - 5696;          // 0..2047
    const int b = lb >> 8;
    const int y = (lb >> 3) & 31;
    const int xseg = lb & 7;
    const int c = threadIdx.x * 2;
    const int x0 = xseg * 4;
    const bool hm = (y > 0), hp = (y < 31);
    float wa[9], wb[9];
#pragma unroll
    for (int k = 0; k < 9; ++k) {
      wa[k] = wdw[(size_t)c * 9 + k];
      wb[k] = wdw[(size_t)(c + 1) * 9 + k];
    }
    const float* xrow = x + ((size_t)b * 1025 + 1) * 512 + c;
    float A0 = 0.f, B0 = 0.f, A1 = 0.f, B1 = 0.f;
    for (int cc = x0 - 1; cc <= x0 + 4; ++cc) {
      float2 v0 = make_float2(0.f, 0.f), v1 = v0, v2 = v0;
      if (cc >= 0 && cc < 32) {
        v1 = *(const float2*)&xrow[((size_t)y * 32 + cc) * 512];
        if (hm) v0 = *(const float2*)&xrow[((size_t)(y - 1) * 32 + cc) * 512];
        if (hp) v2 = *(const float2*)&xrow[((size_t)(y + 1) * 32 + cc) * 512];
      }
      float t0a = v0.x * wa[0] + v1.x * wa[3] + v2.x * wa[6];
      float t1a = v0.x * wa[1] + v1.x * wa[4] + v2.x * wa[7];
      float t2a = v0.x * wa[2] + v1.x * wa[5] + v2.x * wa[8];
      float t0b = v0.y * wb[0] + v1.y * wb[3] + v2.y * wb[6];
      float t1b = v0.y * wb[1] + v1.y * wb[4] + v2.y * wb[7];
      float t2b = v0.y * wb[2] + v1.y * wb[5] + v2.y * wb[8];
      int oc = cc - 1;
      if (oc >= x0 && oc <= x0 + 3) {
        size_t o = ((size_t)b * 1025 + 1 + y * 32 + oc) * 512 + c;
        *(uint32_t*)&locb[o] = pk2(A0 + t2a, A1 + t2b);
      }
      A0 = B0 + t1a; B0 = t0a;
      A1 = B1 + t1b; B1 = t0b;
    }
    if (y == 0 && xseg == 0) {
      float2 xc = *(const float2*)&x[((size_t)b * 1025) * 512 + c];
      *(uint32_t*)&locb[((size_t)b * 1025) * 512 + c] = pk2(xc.x, xc.y);
    }
    return;
  }
  int i = blockIdx.x * 256 + threadIdx.x;
  const float* src = nullptr;
  bf16* dst = nullptr;
  int q = i;
  bool zero = false;
  if (i < 1064960) {
    if (i < 1049600) src = x; else zero = true;
    dst = xb;
  } else if (i < 1064960 + 294912) {
    q = i - 1064960; src = wqkv; dst = wqkvb;
  } else {
    q = i - (1064960 + 294912); src = wout; dst = woutb;
  }
  float4 v = make_float4(0.f, 0.f, 0.f, 0.f);
  if (!zero) v = *(const float4*)&src[(size_t)q * 4];
  uint2 p;
  p.x = pk2(v.x, v.y);
  p.y = pk2(v.z, v.w);
  *(uint2*)&dst[(size_t)q * 4] = p;
}

// Tiled bf16 GEMM, 3-STAGE pipeline (T3+T4): BK=32, triple-buffered LDS,
// counted vmcnt (next stage's LOADS stay in flight) -> prefetch distance 2.
// Chunk swizzle (row>>1)&3. Bijective XCD-chunked 1D grid (m204).
// TPB=512: 8 waves (2x4 wave grid, wave tile 64x32) -> 24 waves/CU at
//   3 blocks/CU (48KB LDS). TPB=256: 4 waves (2x2), as before.
// SWAPPED-OPERAND epilogue: reg r = 4 consecutive CHANNELS, lane l15 = M-row.
// EPI=0 (128x128, NTN=18, TPB=512): scatter q/k (q pre-scaled), V into vP.
// EPI=1 (64x64, NTN=8, TPB=256): +bias, fp32 out, row<8200. Grid 1040.
template <int EPI, int BM, int BN, int NTN, int TPB>
__global__ __launch_bounds__(TPB) void k_gemm(const bf16* __restrict__ A,
                                              const bf16* __restrict__ Bt, int K,
                                              bf16* __restrict__ q, bf16* __restrict__ kk,
                                              bf16* __restrict__ vt,
                                              const float* __restrict__ bias,
                                              float* __restrict__ out) {
  __shared__ __attribute__((aligned(16))) bf16 sA[3][BM * 32];
  __shared__ __attribute__((aligned(16))) bf16 sB[3][BN * 32];
  constexpr int NWAVE = TPB / 64;
  constexpr int WCN = (NWAVE == 8) ? 4 : 2;   // wave-grid cols
  constexpr int WRN = NWAVE / WCN;            // wave-grid rows (=2)
  constexpr int WROWS = BM / WRN, WCOLS = BN / WCN;
  constexpr int MF = WROWS / 16, NF = WCOLS / 16;
  constexpr int AL = BM / 16 / NWAVE;         // A wave-loads per stage
  constexpr int BL = BN / 16 / NWAVE;         // B wave-loads per stage
  constexpr int LOADS = AL + BL;
  const int tid = threadIdx.x;
  const int lane = tid & 63;
  const int w = tid >> 6;
  const int wr = w / WCN, wc = w % WCN;
  const int l15 = lane & 15, l4 = lane >> 4;

  const int nwg = gridDim.x;
  const int qq = nwg >> 3, rr = nwg & 7;
  const int xcd = blockIdx.x & 7, idx = blockIdx.x >> 3;
  const int logical = (xcd < rr) ? xcd * (qq + 1) + idx
                                 : rr * (qq + 1) + (xcd - rr) * qq + idx;
  const int tm = logical / NTN, tn = logical - tm * NTN;

  f32x4 acc[MF][NF] = {};

  // Staging: wave-uniform LDS dest; pre-swizzled per-lane GLOBAL source.
  // Lane covers (row = base + lane>>2, chunk = lane&3); src chunk =
  // (lane&3) ^ ((row>>1)&3). Row blocks of 16 preserve the swizzle.
  const int srow = lane >> 2, schunk = lane & 3;
  const int rA = w * (AL * 16) + srow;
  const bf16* aS = A + ((size_t)(tm * BM + rA)) * K + ((schunk ^ ((rA >> 1) & 3)) * 8);
  const int rB = w * (BL * 16) + srow;
  const bf16* bS = Bt + ((size_t)(tn * BN + rB)) * K + ((schunk ^ ((rB >> 1) & 3)) * 8);

  auto STAGE = [&](int bi, int kt) {
    size_t o = (size_t)kt * 32;
#pragma unroll
    for (int i = 0; i < AL; ++i)
      gload_lds16(aS + (size_t)i * 16 * K + o, &sA[bi][(w * (AL * 16) + i * 16) * 32]);
#pragma unroll
    for (int i = 0; i < BL; ++i)
      gload_lds16(bS + (size_t)i * 16 * K + o, &sB[bi][(w * (BL * 16) + i * 16) * 32]);
  };

  STAGE(0, 0);
  STAGE(1, 1);
  int cur = 0;
  const int Ksteps = K >> 5;
  for (int kt = 0; kt < Ksteps; ++kt) {
    if (kt + 1 < Ksteps) {
      if constexpr (LOADS == 4)      asm volatile("s_waitcnt vmcnt(4)" ::: "memory");
      else if constexpr (LOADS == 3) asm volatile("s_waitcnt vmcnt(3)" ::: "memory");
      else                           asm volatile("s_waitcnt vmcnt(2)" ::: "memory");
    } else {
      asm volatile("s_waitcnt vmcnt(0)" ::: "memory");
    }
    __builtin_amdgcn_s_barrier();
    __builtin_amdgcn_sched_barrier(0);
    if (kt + 2 < Ksteps) {
      int b2 = cur + 2; if (b2 >= 3) b2 -= 3;
      STAGE(b2, kt + 2);
    }

    const bf16* a_ = sA[cur];
    const bf16* b_ = sB[cur];
    bf16x8 af[MF], bfr[NF];
#pragma unroll
    for (int mf = 0; mf < MF; ++mf) {
      int row = wr * WROWS + mf * 16 + l15;
      int phys = l4 ^ ((row >> 1) & 3);
      af[mf] = *(const bf16x8*)&a_[row * 32 + phys * 8];
    }
#pragma unroll
    for (int nf = 0; nf < NF; ++nf) {
      int row = wc * WCOLS + nf * 16 + l15;
      int phys = l4 ^ ((row >> 1) & 3);
      bfr[nf] = *(const bf16x8*)&b_[row * 32 + phys * 8];
    }
    __builtin_amdgcn_s_setprio(1);
#pragma unroll
    for (int mf = 0; mf < MF; ++mf)
#pragma unroll
      for (int nf = 0; nf < NF; ++nf)
        acc[mf][nf] =
            __builtin_amdgcn_mfma_f32_16x16x32_bf16(bfr[nf], af[mf], acc[mf][nf], 0, 0, 0);
    __builtin_amdgcn_s_setprio(0);
    ++cur; if (cur >= 3) cur = 0;
  }

  const int RbaseL = tm * BM + wr * WROWS + l15;
  const int CbaseL = tn * BN + wc * WCOLS + l4 * 4;
#pragma unroll
  for (int mf = 0; mf < MF; ++mf) {
    int R = RbaseL + mf * 16;
    if (R >= 8200) continue;
    if (EPI == 0) {
      int b = R / 1025;
      int n = R - b * 1025;
      int kvq = n >> 2, e = n & 3;
#pragma unroll
      for (int nf = 0; nf < NF; ++nf) {
        int Cc0 = CbaseL + nf * 16;                 // 4-aligned; 4 vals same seg
        int seg = (Cc0 >= 1536) ? 2 : (Cc0 >= 768 ? 1 : 0);
        int inner = Cc0 - seg * 768;
        int h = inner >> 6, d0 = inner & 63;        // d0..d0+3 within same head
        if (seg == 2) {
          bf16* vb = &vt[(((size_t)(b * 12 + h) * 272 + kvq) * 64 + d0) * 4 + e];
#pragma unroll
          for (int r = 0; r < 4; ++r) vb[r * 4] = (bf16)acc[mf][nf][r];
        } else {
          bf16* dst = seg ? kk : q;
          float scl = seg ? 1.f : QSCALE;
          uint2 p;
          p.x = pk2(acc[mf][nf][0] * scl, acc[mf][nf][1] * scl);
          p.y = pk2(acc[mf][nf][2] * scl, acc[mf][nf][3] * scl);
          *(uint2*)&dst[(((size_t)b * 12 + h) * 1088 + n) * 64 + d0] = p;
        }
      }
    } else {
#pragma unroll
      for (int nf = 0; nf < NF; ++nf) {
        int Cc0 = CbaseL + nf * 16;
        float4 bz = *(const float4*)&bias[Cc0];
        float4 o4;
        o4.x = acc[mf][nf][0] + bz.x;
        o4.y = acc[mf][nf][1] + bz.y;
        o4.z = acc[mf][nf][2] + bz.z;
        o4.w = acc[mf][nf][3] + bz.w;
        *(float4*)&out[(size_t)R * 512 + Cc0] = o4;
      }
    }
  }
}

// Flash attention, swapped-QK^T, double-buffered K/V, shift-free softmax.
// 8 WAVES per block (512 thr), 128 q-rows/block, grid 864 (= 8*108, exact
// XCD-bijective): 4 blocks/CU x 8 waves = 32 waves/CU, single dispatch round.
// 16 full KV tiles + rank-1 tail. PV via mfma_16x16x16 (P in-register).
// Epilogue fuses the depthwise-conv local branch: adds locb for heads h<8.
// LDS = 32768 B. NOTE: no min-waves launch_bounds (round-4 spill lesson).
__global__ __launch_bounds__(512) void k_flash(const bf16* __restrict__ qg,
                                               const bf16* __restrict__ kg,
                                               const bf16* __restrict__ vpg,
                                               const bf16* __restrict__ locb,
                                               bf16* __restrict__ outb) {
  __shared__ __attribute__((aligned(16))) bf16 sK[2][64 * 64];
  __shared__ __attribute__((aligned(16))) bf16 sVP[2][16 * 256];  // 16 kvq x 64 d x 4 e
  const int tid = threadIdx.x, lane = tid & 63, w = tid >> 6;  // w = 0..7
  const int l15 = lane & 15, l4 = lane >> 4;
  // XCD-contiguous mapping: 864 = 8 * 108
  const int wg = blockIdx.x;
  const int logical = (wg & 7) * 108 + (wg >> 3);
  const int bh = logical / 9, qgp = logical - bh * 9;   // 9 q-groups of 128
  const int b = bh / 12, h = bh - b * 12;

  // Q fragments (pre-scaled by QSCALE in the QKV GEMM epilogue)
  size_t qoff = ((size_t)bh * 1088 + qgp * 128 + w * 16 + l15) * 64 + l4 * 8;
  const bf16x8 qf0 = *(const bf16x8*)&qg[qoff];
  const bf16x8 qf1 = *(const bf16x8*)&qg[qoff + 32];

  float lreg = 0.f;  // per-lane partial row sum (reduced in epilogue)
  f32x4 oa[4] = {};

  const int px0 = (l4 ^ (l15 & 7)) * 8;        // K LDS swizzled chunk, ks=0
  const int px1 = ((4 + l4) ^ (l15 & 7)) * 8;  // ks=1

  // Staging: wave w covers K rows [w*8, w*8+8) (1 gload/wave) and V elements
  // [w*512, (w+1)*512) (1 gload/wave). Both tiles advance 4096 elems per t.
  const int rowK = w * 8 + (lane >> 3);
  const int clogK = (lane & 7) ^ (rowK & 7);
  const bf16* kS = kg + ((size_t)bh * 1088 + rowK) * 64 + clogK * 8;
  const bf16* vS = vpg + (size_t)bh * 69632 + w * 512 + lane * 8;
  const int kD = w * 512;   // wave-uniform LDS elem base (lane adds *8)
  const int vD = w * 512;

  auto STAGE = [&](int bi, int t) {
    size_t o = (size_t)t * 4096;
    gload_lds16(kS + o, &sK[bi][kD]);
    gload_lds16(vS + o, &sVP[bi][vD]);
  };

  STAGE(0, 0);
  int cur = 0;

  for (int t = 0; t < 16; ++t) {
    // Wait this tile's loads (issued one full iteration ago), converge. After
    // the barrier all waves consumed buf[cur^1] -> restage is race-free.
    asm volatile("s_waitcnt vmcnt(0)" ::: "memory");
    __builtin_amdgcn_s_barrier();
    __builtin_amdgcn_sched_barrier(0);
    if (t < 15) STAGE(cur ^ 1, t + 1);

    const bf16* kb_ = sK[cur];
    const bf16* vpb = sVP[cur];

    // S^T = K · Q^T : lane holds S[q=l15][kv = jt*16 + l4*4 + r]
    f32x4 sc[4] = {};
    __builtin_amdgcn_s_setprio(1);
#pragma unroll
    for (int jt = 0; jt < 4; ++jt) {
      bf16x8 a0 = *(const bf16x8*)&kb_[(jt * 16 + l15) * 64 + px0];
      sc[jt] = __builtin_amdgcn_mfma_f32_16x16x32_bf16(a0, qf0, sc[jt], 0, 0, 0);
    }
#pragma unroll
    for (int jt = 0; jt < 4; ++jt) {
      bf16x8 a1 = *(const bf16x8*)&kb_[(jt * 16 + l15) * 64 + px1];
      sc[jt] = __builtin_amdgcn_mfma_f32_16x16x32_bf16(a1, qf1, sc[jt], 0, 0, 0);
    }
    __builtin_amdgcn_s_setprio(0);

    // P = exp2(S); pack per-jt into the 16x16x16 A-fragment directly.
    union { uint32_t u[2]; s4 v; } pa[4];
    float lsum = 0.f;
#pragma unroll
    for (int jt = 0; jt < 4; ++jt) {
      float p0 = fexp2(sc[jt][0]);
      float p1 = fexp2(sc[jt][1]);
      float p2 = fexp2(sc[jt][2]);
      float p3 = fexp2(sc[jt][3]);
      lsum += (p0 + p1) + (p2 + p3);
      pa[jt].u[0] = pk2(p0, p1);
      pa[jt].u[1] = pk2(p2, p3);
    }
    lreg += lsum;

    // O += P · V  (16 x mfma_16x16x16, A = in-register P)
    __builtin_amdgcn_s_setprio(1);
#pragma unroll
    for (int jt = 0; jt < 4; ++jt)
#pragma unroll
      for (int db = 0; db < 4; ++db) {
        s4 vf = *(const s4*)&vpb[((jt * 4 + l4) * 64 + db * 16 + l15) * 4];
        oa[db] = pv_mfma(pa[jt].v, vf, oa[db]);
      }
    __builtin_amdgcn_s_setprio(0);
    cur ^= 1;
  }

  // Rank-1 tail: kv = 1024.
  {
    const bf16* k1 = kg + ((size_t)bh * 1088 + 1024) * 64;
    bf16x8 kA = *(const bf16x8*)&k1[l4 * 8];
    bf16x8 kB = *(const bf16x8*)&k1[32 + l4 * 8];
    float s = 0.f;
#pragma unroll
    for (int e = 0; e < 8; ++e)
      s += (float)qf0[e] * (float)kA[e] + (float)qf1[e] * (float)kB[e];
    s += __shfl_xor(s, 16);
    s += __shfl_xor(s, 32);
    float p = fexp2(s);
    if (l4 == 0) lreg += p;  // count once per q-row (epilogue sums l4 copies)
    float pr[4];
#pragma unroll
    for (int r = 0; r < 4; ++r) pr[r] = __shfl(p, l4 * 4 + r);
    const bf16* v1 = vpg + (size_t)bh * 69632 + 65536;  // kvq=256, e=0
#pragma unroll
    for (int db = 0; db < 4; ++db) {
      float vd = (float)v1[(db * 16 + l15) * 4];
#pragma unroll
      for (int r = 0; r < 4; ++r) oa[db][r] += pr[r] * vd;
    }
  }

  float ls = lreg;
  ls += __shfl_xor(ls, 16);
  ls += __shfl_xor(ls, 32);
  float linv = frcp(ls);
#pragma unroll
  for (int r = 0; r < 4; ++r) {
    float ir = __shfl(linv, l4 * 4 + r);
    int n = qgp * 128 + w * 16 + l4 * 4 + r;
    if (n >= 1025) continue;
#pragma unroll
    for (int db = 0; db < 4; ++db) {
      float v = oa[db][r] * ir;
      if (h < 8)
        v += (float)locb[((size_t)b * 1025 + n) * 512 + h * 64 + db * 16 + l15];
      outb[((size_t)b * 1025 + n) * 768 + h * 64 + db * 16 + l15] = (bf16)v;
    }
  }
}

extern "C" void kernel_launch(void* const* d_in, const int* in_sizes, int n_in,
                              void* d_out, int out_size, void* d_ws, size_t ws_size,
                              hipStream_t stream) {
  const float* x = (const float*)d_in[0];
  const float* w_qkv = (const float*)d_in[1];
  const float* w_dw = (const float*)d_in[2];
  const float* w_out = (const float*)d_in[3];
  const float* b_out = (const float*)d_in[4];
  float* out = (float*)d_out;

  char* ws = (char*)d_ws;
  size_t off = 0;
  auto alloc = [&](size_t bytes) {
    char* p = ws + off;
    off = (off + bytes + 255) & ~(size_t)255;
    return p;
  };
  bf16* xb    = (bf16*)alloc((size_t)8320 * 512 * 2);
  bf16* wqkvb = (bf16*)alloc((size_t)2304 * 512 * 2);
  bf16* woutb = (bf16*)alloc((size_t)512 * 768 * 2);
  bf16* qb    = (bf16*)alloc((size_t)96 * 1088 * 64 * 2);
  bf16* kb    = (bf16*)alloc((size_t)96 * 1088 * 64 * 2);
  bf16* vP    = (bf16*)alloc((size_t)96 * 272 * 64 * 4 * 2);  // 69632 elems/head
  bf16* locb  = (bf16*)alloc((size_t)8 * 1025 * 512 * 2);
  bf16* outb  = (bf16*)alloc((size_t)8320 * 768 * 2);

  // Fused prep + conv: 5696 prep blocks + 2048 conv blocks
  k_prep<<<7744, 256, 0, stream>>>(x, w_qkv, w_out, xb, wqkvb, woutb, w_dw, locb);
  // 1170 = 65*18 blocks (128x128 tiles, 8 waves), XCD-chunked inside kernel
  k_gemm<0, 128, 128, 18, 512><<<1170, 512, 0, stream>>>(xb, wqkvb, 512, qb, kb, vP,
                                                         nullptr, nullptr);
  k_flash<<<864, 512, 0, stream>>>(qb, kb, vP, locb, outb);
  // 1040 = 130*8 blocks
  k_gemm<1, 64, 64, 8, 256><<<1040, 256, 0, stream>>>(outb, woutb, 768, nullptr, nullptr,
                                                      nullptr, b_out, out);
}

// Round 23
// 129.903 us; speedup vs baseline: 1.0482x; 1.0048x over previous
//
#include <hip/hip_runtime.h>
#include <hip/hip_bf16.h>
#include <stdint.h>
#include <math.h>

typedef __bf16 bf16;
typedef __bf16 bf16x8 __attribute__((ext_vector_type(8)));
typedef float f32x4 __attribute__((ext_vector_type(4)));
typedef short s4 __attribute__((ext_vector_type(4)));  // 4 bf16 (2 VGPR)

#define QSCALE 0.1803368801111f  /* 0.125 * log2(e) */

// B=8, N=1025 (32*32+1), DIM=512, HEADS=12, DH=64, INNER=768
// M = 8*1025 = 8200, padded to 8320. KV per (b,h): 1025 = 16*64 + 1 -> 16 full
// tiles + rank-1 tail (kv=1024) handled in-register.
// V layout "vP": per head [kvq=272][d=64][e=4], kv = kvq*4+e.
// PV uses mfma_f32_16x16x16_bf16 whose A-fragment (lane: A[l15][4*l4+e])
// exactly matches the swapped-QK^T P ownership; no cross-lane P movement.
// Softmax: shift-free (scores exp2-domain max ~8.3 -> p<=~300, FP-safe).
// ROUND-16: V must come from LDS. ROUND-18: ones-MFMA denominator loses.
// ROUND-19/20: flash was wave-limited; 8-wave blocks fixed it.
// ROUND-21: gemm0 is at its 1-phase structure-family ceiling (363 TF).
// ROUND-22 BUG: vec8 prep boundaries were old 4-elem-unit counts / 8 instead
// of element counts / 8 -> only 1/4 of the weights converted. Fixed: unit
// boundaries are ELEMENT counts / 8: xb 532480 (src 524800), wqkv 147456,
// wout 49152; prep blocks 2848; conv offset 2848.

__device__ __forceinline__ void gload_lds16(const void* g, void* l) {
  typedef const __attribute__((address_space(1))) char g_char;
  typedef __attribute__((address_space(3))) char l_char;
  g_char* gp = (g_char*)(uintptr_t)g;
  l_char* lp = (l_char*)(uint32_t)(uintptr_t)l;
  __builtin_amdgcn_global_load_lds(gp, lp, 16, 0, 0);
}

__device__ __forceinline__ float fexp2(float x) {
#if __has_builtin(__builtin_amdgcn_exp2f)
  return __builtin_amdgcn_exp2f(x);
#else
  return exp2f(x);
#endif
}

__device__ __forceinline__ float frcp(float x) {
#if __has_builtin(__builtin_amdgcn_rcpf)
  return __builtin_amdgcn_rcpf(x);
#else
  return 1.f / x;
#endif
}

__device__ __forceinline__ uint32_t pk2(float a, float b) {
  union { bf16 h; unsigned short u; } ua, ub;
  ua.h = (bf16)a; ub.h = (bf16)b;
  return (uint32_t)ua.u | ((uint32_t)ub.u << 16);
}

__device__ __forceinline__ f32x4 pv_mfma(s4 a, s4 b, f32x4 c) {
#if __has_builtin(__builtin_amdgcn_mfma_f32_16x16x16bf16_1k)
  return __builtin_amdgcn_mfma_f32_16x16x16bf16_1k(a, b, c, 0, 0, 0);
#else
  asm volatile("v_mfma_f32_16x16x16_bf16 %0, %1, %2, %0" : "+v"(c) : "v"(a), "v"(b));
  return c;
#endif
}

// FUSED prep + depthwise conv. Blocks [0,2848): vec8 convert — x->xb (pad to
// 8320 rows), w_qkv->bf16, w_out->bf16 (8 elems/thread: 2 float4 -> 1 uint4).
// 8-elem-unit boundaries: xb 532480 (src valid 524800), wqkv 147456, wout
// 49152; total 729088 = 2848*256. Blocks [2848,4896): 3x3 depthwise conv
// (SAME) + cls passthrough -> locb (B,1025,512) bf16, no RMW (added in flash).
__global__ __launch_bounds__(256) void k_prep(const float* __restrict__ x,
                                              const float* __restrict__ wqkv,
                                              const float* __restrict__ wout,
                                              bf16* __restrict__ xb, bf16* __restrict__ wqkvb,
                                              bf16* __restrict__ woutb,
                                              const float* __restrict__ wdw,
                                              bf16* __restrict__ locb) {
  if (blockIdx.x >= 2848) {
    const int lb = blockIdx.x - 2848;          // 0..2047
    const int b = lb >> 8;
    const int y = (lb >> 3) & 31;
    const int xseg = lb & 7;
    const int c = threadIdx.x * 2;
    const int x0 = xseg * 4;
    const bool hm = (y > 0), hp = (y < 31);
    float wa[9], wb[9];
#pragma unroll
    for (int k = 0; k < 9; ++k) {
      wa[k] = wdw[(size_t)c * 9 + k];
      wb[k] = wdw[(size_t)(c + 1) * 9 + k];
    }
    const float* xrow = x + ((size_t)b * 1025 + 1) * 512 + c;
    float A0 = 0.f, B0 = 0.f, A1 = 0.f, B1 = 0.f;
    for (int cc = x0 - 1; cc <= x0 + 4; ++cc) {
      float2 v0 = make_float2(0.f, 0.f), v1 = v0, v2 = v0;
      if (cc >= 0 && cc < 32) {
        v1 = *(const float2*)&xrow[((size_t)y * 32 + cc) * 512];
        if (hm) v0 = *(const float2*)&xrow[((size_t)(y - 1) * 32 + cc) * 512];
        if (hp) v2 = *(const float2*)&xrow[((size_t)(y + 1) * 32 + cc) * 512];
      }
      float t0a = v0.x * wa[0] + v1.x * wa[3] + v2.x * wa[6];
      float t1a = v0.x * wa[1] + v1.x * wa[4] + v2.x * wa[7];
      float t2a = v0.x * wa[2] + v1.x * wa[5] + v2.x * wa[8];
      float t0b = v0.y * wb[0] + v1.y * wb[3] + v2.y * wb[6];
      float t1b = v0.y * wb[1] + v1.y * wb[4] + v2.y * wb[7];
      float t2b = v0.y * wb[2] + v1.y * wb[5] + v2.y * wb[8];
      int oc = cc - 1;
      if (oc >= x0 && oc <= x0 + 3) {
        size_t o = ((size_t)b * 1025 + 1 + y * 32 + oc) * 512 + c;
        *(uint32_t*)&locb[o] = pk2(A0 + t2a, A1 + t2b);
      }
      A0 = B0 + t1a; B0 = t0a;
      A1 = B1 + t1b; B1 = t0b;
    }
    if (y == 0 && xseg == 0) {
      float2 xc = *(const float2*)&x[((size_t)b * 1025) * 512 + c];
      *(uint32_t*)&locb[((size_t)b * 1025) * 512 + c] = pk2(xc.x, xc.y);
    }
    return;
  }
  // ---- vec8 prep branch (u = 8-elem unit index)
  int u = blockIdx.x * 256 + threadIdx.x;
  const float* src = nullptr;
  bf16* dst = nullptr;
  bool zero = false;
  if (u < 532480) {
    if (u >= 524800) zero = true;
    src = x; dst = xb;
  } else if (u < 679936) {
    u -= 532480; src = wqkv; dst = wqkvb;
  } else {
    u -= 679936; src = wout; dst = woutb;
  }
  float4 a = make_float4(0.f, 0.f, 0.f, 0.f), bq = a;
  if (!zero) {
    a  = *(const float4*)&src[(size_t)u * 8];
    bq = *(const float4*)&src[(size_t)u * 8 + 4];
  }
  uint4 p;
  p.x = pk2(a.x, a.y);
  p.y = pk2(a.z, a.w);
  p.z = pk2(bq.x, bq.y);
  p.w = pk2(bq.z, bq.w);
  *(uint4*)&dst[(size_t)u * 8] = p;
}

// Tiled bf16 GEMM, 3-STAGE pipeline (T3+T4): BK=32, triple-buffered LDS,
// counted vmcnt (next stage's LOADS stay in flight) -> prefetch distance 2.
// Chunk swizzle (row>>1)&3. Bijective XCD-chunked 1D grid (m204).
// TPB=512: 8 waves (2x4 grid, wave tile 64x32). TPB=256: 4 waves (2x2).
// SWAPPED-OPERAND epilogue: reg r = 4 consecutive CHANNELS, lane l15 = M-row.
// EPI=0 (128x128, NTN=18, TPB=512): scatter q/k (q pre-scaled), V into vP.
// EPI=1 (128x64, NTN=8, TPB=256): +bias, fp32 out, row<8200. Grid 520;
//   8 MFMA/step/wave (the old 64x64 issued only 4 between barriers).
template <int EPI, int BM, int BN, int NTN, int TPB>
__global__ __launch_bounds__(TPB) void k_gemm(const bf16* __restrict__ A,
                                              const bf16* __restrict__ Bt, int K,
                                              bf16* __restrict__ q, bf16* __restrict__ kk,
                                              bf16* __restrict__ vt,
                                              const float* __restrict__ bias,
                                              float* __restrict__ out) {
  __shared__ __attribute__((aligned(16))) bf16 sA[3][BM * 32];
  __shared__ __attribute__((aligned(16))) bf16 sB[3][BN * 32];
  constexpr int NWAVE = TPB / 64;
  constexpr int WCN = (NWAVE == 8) ? 4 : 2;   // wave-grid cols
  constexpr int WRN = NWAVE / WCN;            // wave-grid rows (=2)
  constexpr int WROWS = BM / WRN, WCOLS = BN / WCN;
  constexpr int MF = WROWS / 16, NF = WCOLS / 16;
  constexpr int AL = BM / 16 / NWAVE;         // A wave-loads per stage
  constexpr int BL = BN / 16 / NWAVE;         // B wave-loads per stage
  constexpr int LOADS = AL + BL;
  const int tid = threadIdx.x;
  const int lane = tid & 63;
  const int w = tid >> 6;
  const int wr = w / WCN, wc = w % WCN;
  const int l15 = lane & 15, l4 = lane >> 4;

  const int nwg = gridDim.x;
  const int qq = nwg >> 3, rr = nwg & 7;
  const int xcd = blockIdx.x & 7, idx = blockIdx.x >> 3;
  const int logical = (xcd < rr) ? xcd * (qq + 1) + idx
                                 : rr * (qq + 1) + (xcd - rr) * qq + idx;
  const int tm = logical / NTN, tn = logical - tm * NTN;

  f32x4 acc[MF][NF] = {};

  const int srow = lane >> 2, schunk = lane & 3;
  const int rA = w * (AL * 16) + srow;
  const bf16* aS = A + ((size_t)(tm * BM + rA)) * K + ((schunk ^ ((rA >> 1) & 3)) * 8);
  const int rB = w * (BL * 16) + srow;
  const bf16* bS = Bt + ((size_t)(tn * BN + rB)) * K + ((schunk ^ ((rB >> 1) & 3)) * 8);

  auto STAGE = [&](int bi, int kt) {
    size_t o = (size_t)kt * 32;
#pragma unroll
    for (int i = 0; i < AL; ++i)
      gload_lds16(aS + (size_t)i * 16 * K + o, &sA[bi][(w * (AL * 16) + i * 16) * 32]);
#pragma unroll
    for (int i = 0; i < BL; ++i)
      gload_lds16(bS + (size_t)i * 16 * K + o, &sB[bi][(w * (BL * 16) + i * 16) * 32]);
  };

  STAGE(0, 0);
  STAGE(1, 1);
  int cur = 0;
  const int Ksteps = K >> 5;
  for (int kt = 0; kt < Ksteps; ++kt) {
    if (kt + 1 < Ksteps) {
      if constexpr (LOADS == 4)      asm volatile("s_waitcnt vmcnt(4)" ::: "memory");
      else if constexpr (LOADS == 3) asm volatile("s_waitcnt vmcnt(3)" ::: "memory");
      else                           asm volatile("s_waitcnt vmcnt(2)" ::: "memory");
    } else {
      asm volatile("s_waitcnt vmcnt(0)" ::: "memory");
    }
    __builtin_amdgcn_s_barrier();
    __builtin_amdgcn_sched_barrier(0);
    if (kt + 2 < Ksteps) {
      int b2 = cur + 2; if (b2 >= 3) b2 -= 3;
      STAGE(b2, kt + 2);
    }

    const bf16* a_ = sA[cur];
    const bf16* b_ = sB[cur];
    bf16x8 af[MF], bfr[NF];
#pragma unroll
    for (int mf = 0; mf < MF; ++mf) {
      int row = wr * WROWS + mf * 16 + l15;
      int phys = l4 ^ ((row >> 1) & 3);
      af[mf] = *(const bf16x8*)&a_[row * 32 + phys * 8];
    }
#pragma unroll
    for (int nf = 0; nf < NF; ++nf) {
      int row = wc * WCOLS + nf * 16 + l15;
      int phys = l4 ^ ((row >> 1) & 3);
      bfr[nf] = *(const bf16x8*)&b_[row * 32 + phys * 8];
    }
    __builtin_amdgcn_s_setprio(1);
#pragma unroll
    for (int mf = 0; mf < MF; ++mf)
#pragma unroll
      for (int nf = 0; nf < NF; ++nf)
        acc[mf][nf] =
            __builtin_amdgcn_mfma_f32_16x16x32_bf16(bfr[nf], af[mf], acc[mf][nf], 0, 0, 0);
    __builtin_amdgcn_s_setprio(0);
    ++cur; if (cur >= 3) cur = 0;
  }

  const int RbaseL = tm * BM + wr * WROWS + l15;
  const int CbaseL = tn * BN + wc * WCOLS + l4 * 4;
#pragma unroll
  for (int mf = 0; mf < MF; ++mf) {
    int R = RbaseL + mf * 16;
    if (R >= 8200) continue;
    if (EPI == 0) {
      int b = R / 1025;
      int n = R - b * 1025;
      int kvq = n >> 2, e = n & 3;
#pragma unroll
      for (int nf = 0; nf < NF; ++nf) {
        int Cc0 = CbaseL + nf * 16;                 // 4-aligned; 4 vals same seg
        int seg = (Cc0 >= 1536) ? 2 : (Cc0 >= 768 ? 1 : 0);
        int inner = Cc0 - seg * 768;
        int h = inner >> 6, d0 = inner & 63;        // d0..d0+3 within same head
        if (seg == 2) {
          bf16* vb = &vt[(((size_t)(b * 12 + h) * 272 + kvq) * 64 + d0) * 4 + e];
#pragma unroll
          for (int r = 0; r < 4; ++r) vb[r * 4] = (bf16)acc[mf][nf][r];
        } else {
          bf16* dst = seg ? kk : q;
          float scl = seg ? 1.f : QSCALE;
          uint2 p;
          p.x = pk2(acc[mf][nf][0] * scl, acc[mf][nf][1] * scl);
          p.y = pk2(acc[mf][nf][2] * scl, acc[mf][nf][3] * scl);
          *(uint2*)&dst[(((size_t)b * 12 + h) * 1088 + n) * 64 + d0] = p;
        }
      }
    } else {
#pragma unroll
      for (int nf = 0; nf < NF; ++nf) {
        int Cc0 = CbaseL + nf * 16;
        float4 bz = *(const float4*)&bias[Cc0];
        float4 o4;
        o4.x = acc[mf][nf][0] + bz.x;
        o4.y = acc[mf][nf][1] + bz.y;
        o4.z = acc[mf][nf][2] + bz.z;
        o4.w = acc[mf][nf][3] + bz.w;
        *(float4*)&out[(size_t)R * 512 + Cc0] = o4;
      }
    }
  }
}

// Flash attention, swapped-QK^T, double-buffered K/V, shift-free softmax.
// 8 WAVES per block (512 thr), 128 q-rows/block, grid 864 (= 8*108, exact
// XCD-bijective): 4 blocks/CU x 8 waves = 32 waves/CU, single dispatch round.
// 16 full KV tiles + rank-1 tail. PV via mfma_16x16x16 (P in-register).
// Epilogue fuses the depthwise-conv local branch: adds locb for heads h<8.
// LDS = 32768 B. NOTE: no min-waves launch_bounds (round-4 spill lesson).
__global__ __launch_bounds__(512) void k_flash(const bf16* __restrict__ qg,
                                               const bf16* __restrict__ kg,
                                               const bf16* __restrict__ vpg,
                                               const bf16* __restrict__ locb,
                                               bf16* __restrict__ outb) {
  __shared__ __attribute__((aligned(16))) bf16 sK[2][64 * 64];
  __shared__ __attribute__((aligned(16))) bf16 sVP[2][16 * 256];  // 16 kvq x 64 d x 4 e
  const int tid = threadIdx.x, lane = tid & 63, w = tid >> 6;  // w = 0..7
  const int l15 = lane & 15, l4 = lane >> 4;
  // XCD-contiguous mapping: 864 = 8 * 108
  const int wg = blockIdx.x;
  const int logical = (wg & 7) * 108 + (wg >> 3);
  const int bh = logical / 9, qgp = logical - bh * 9;   // 9 q-groups of 128
  const int b = bh / 12, h = bh - b * 12;

  // Q fragments (pre-scaled by QSCALE in the QKV GEMM epilogue)
  size_t qoff = ((size_t)bh * 1088 + qgp * 128 + w * 16 + l15) * 64 + l4 * 8;
  const bf16x8 qf0 = *(const bf16x8*)&qg[qoff];
  const bf16x8 qf1 = *(const bf16x8*)&qg[qoff + 32];

  float lreg = 0.f;  // per-lane partial row sum (reduced in epilogue)
  f32x4 oa[4] = {};

  const int px0 = (l4 ^ (l15 & 7)) * 8;        // K LDS swizzled chunk, ks=0
  const int px1 = ((4 + l4) ^ (l15 & 7)) * 8;  // ks=1

  // Staging: wave w covers K rows [w*8, w*8+8) (1 gload/wave) and V elements
  // [w*512, (w+1)*512) (1 gload/wave). Both tiles advance 4096 elems per t.
  const int rowK = w * 8 + (lane >> 3);
  const int clogK = (lane & 7) ^ (rowK & 7);
  const bf16* kS = kg + ((size_t)bh * 1088 + rowK) * 64 + clogK * 8;
  const bf16* vS = vpg + (size_t)bh * 69632 + w * 512 + lane * 8;
  const int kD = w * 512;   // wave-uniform LDS elem base (lane adds *8)
  const int vD = w * 512;

  auto STAGE = [&](int bi, int t) {
    size_t o = (size_t)t * 4096;
    gload_lds16(kS + o, &sK[bi][kD]);
    gload_lds16(vS + o, &sVP[bi][vD]);
  };

  STAGE(0, 0);
  int cur = 0;

  for (int t = 0; t < 16; ++t) {
    // Wait this tile's loads (issued one full iteration ago), converge. After
    // the barrier all waves consumed buf[cur^1] -> restage is race-free.
    asm volatile("s_waitcnt vmcnt(0)" ::: "memory");
    __builtin_amdgcn_s_barrier();
    __builtin_amdgcn_sched_barrier(0);
    if (t < 15) STAGE(cur ^ 1, t + 1);

    const bf16* kb_ = sK[cur];
    const bf16* vpb = sVP[cur];

    // S^T = K · Q^T : lane holds S[q=l15][kv = jt*16 + l4*4 + r]
    f32x4 sc[4] = {};
    __builtin_amdgcn_s_setprio(1);
#pragma unroll
    for (int jt = 0; jt < 4; ++jt) {
      bf16x8 a0 = *(const bf16x8*)&kb_[(jt * 16 + l15) * 64 + px0];
      sc[jt] = __builtin_amdgcn_mfma_f32_16x16x32_bf16(a0, qf0, sc[jt], 0, 0, 0);
    }
#pragma unroll
    for (int jt = 0; jt < 4; ++jt) {
      bf16x8 a1 = *(const bf16x8*)&kb_[(jt * 16 + l15) * 64 + px1];
      sc[jt] = __builtin_amdgcn_mfma_f32_16x16x32_bf16(a1, qf1, sc[jt], 0, 0, 0);
    }
    __builtin_amdgcn_s_setprio(0);

    // P = exp2(S); pack per-jt into the 16x16x16 A-fragment directly.
    union { uint32_t u[2]; s4 v; } pa[4];
    float lsum = 0.f;
#pragma unroll
    for (int jt = 0; jt < 4; ++jt) {
      float p0 = fexp2(sc[jt][0]);
      float p1 = fexp2(sc[jt][1]);
      float p2 = fexp2(sc[jt][2]);
      float p3 = fexp2(sc[jt][3]);
      lsum += (p0 + p1) + (p2 + p3);
      pa[jt].u[0] = pk2(p0, p1);
      pa[jt].u[1] = pk2(p2, p3);
    }
    lreg += lsum;

    // O += P · V  (16 x mfma_16x16x16, A = in-register P)
    __builtin_amdgcn_s_setprio(1);
#pragma unroll
    for (int jt = 0; jt < 4; ++jt)
#pragma unroll
      for (int db = 0; db < 4; ++db) {
        s4 vf = *(const s4*)&vpb[((jt * 4 + l4) * 64 + db * 16 + l15) * 4];
        oa[db] = pv_mfma(pa[jt].v, vf, oa[db]);
      }
    __builtin_amdgcn_s_setprio(0);
    cur ^= 1;
  }

  // Rank-1 tail: kv = 1024.
  {
    const bf16* k1 = kg + ((size_t)bh * 1088 + 1024) * 64;
    bf16x8 kA = *(const bf16x8*)&k1[l4 * 8];
    bf16x8 kB = *(const bf16x8*)&k1[32 + l4 * 8];
    float s = 0.f;
#pragma unroll
    for (int e = 0; e < 8; ++e)
      s += (float)qf0[e] * (float)kA[e] + (float)qf1[e] * (float)kB[e];
    s += __shfl_xor(s, 16);
    s += __shfl_xor(s, 32);
    float p = fexp2(s);
    if (l4 == 0) lreg += p;  // count once per q-row (epilogue sums l4 copies)
    float pr[4];
#pragma unroll
    for (int r = 0; r < 4; ++r) pr[r] = __shfl(p, l4 * 4 + r);
    const bf16* v1 = vpg + (size_t)bh * 69632 + 65536;  // kvq=256, e=0
#pragma unroll
    for (int db = 0; db < 4; ++db) {
      float vd = (float)v1[(db * 16 + l15) * 4];
#pragma unroll
      for (int r = 0; r < 4; ++r) oa[db][r] += pr[r] * vd;
    }
  }

  float ls = lreg;
  ls += __shfl_xor(ls, 16);
  ls += __shfl_xor(ls, 32);
  float linv = frcp(ls);
#pragma unroll
  for (int r = 0; r < 4; ++r) {
    float ir = __shfl(linv, l4 * 4 + r);
    int n = qgp * 128 + w * 16 + l4 * 4 + r;
    if (n >= 1025) continue;
#pragma unroll
    for (int db = 0; db < 4; ++db) {
      float v = oa[db][r] * ir;
      if (h < 8)
        v += (float)locb[((size_t)b * 1025 + n) * 512 + h * 64 + db * 16 + l15];
      outb[((size_t)b * 1025 + n) * 768 + h * 64 + db * 16 + l15] = (bf16)v;
    }
  }
}

extern "C" void kernel_launch(void* const* d_in, const int* in_sizes, int n_in,
                              void* d_out, int out_size, void* d_ws, size_t ws_size,
                              hipStream_t stream) {
  const float* x = (const float*)d_in[0];
  const float* w_qkv = (const float*)d_in[1];
  const float* w_dw = (const float*)d_in[2];
  const float* w_out = (const float*)d_in[3];
  const float* b_out = (const float*)d_in[4];
  float* out = (float*)d_out;

  char* ws = (char*)d_ws;
  size_t off = 0;
  auto alloc = [&](size_t bytes) {
    char* p = ws + off;
    off = (off + bytes + 255) & ~(size_t)255;
    return p;
  };
  bf16* xb    = (bf16*)alloc((size_t)8320 * 512 * 2);
  bf16* wqkvb = (bf16*)alloc((size_t)2304 * 512 * 2);
  bf16* woutb = (bf16*)alloc((size_t)512 * 768 * 2);
  bf16* qb    = (bf16*)alloc((size_t)96 * 1088 * 64 * 2);
  bf16* kb    = (bf16*)alloc((size_t)96 * 1088 * 64 * 2);
  bf16* vP    = (bf16*)alloc((size_t)96 * 272 * 64 * 4 * 2);  // 69632 elems/head
  bf16* locb  = (bf16*)alloc((size_t)8 * 1025 * 512 * 2);
  bf16* outb  = (bf16*)alloc((size_t)8320 * 768 * 2);

  // Fused prep (vec8: 2848 blocks) + conv (2048 blocks)
  k_prep<<<4896, 256, 0, stream>>>(x, w_qkv, w_out, xb, wqkvb, woutb, w_dw, locb);
  // 1170 = 65*18 blocks (128x128 tiles, 8 waves), XCD-chunked inside kernel
  k_gemm<0, 128, 128, 18, 512><<<1170, 512, 0, stream>>>(xb, wqkvb, 512, qb, kb, vP,
                                                         nullptr, nullptr);
  k_flash<<<864, 512, 0, stream>>>(qb, kb, vP, locb, outb);
  // 520 = 65*8 blocks (128x64 tiles, 4 waves)
  k_gemm<1, 128, 64, 8, 256><<<520, 256, 0, stream>>>(outb, woutb, 768, nullptr, nullptr,
                                                      nullptr, b_out, out);
}

// Round 24
// 128.460 us; speedup vs baseline: 1.0600x; 1.0112x over previous
//
#include <hip/hip_runtime.h>
#include <hip/hip_bf16.h>
#include <stdint.h>
#include <math.h>

typedef __bf16 bf16;
typedef __bf16 bf16x8 __attribute__((ext_vector_type(8)));
typedef float f32x4 __attribute__((ext_vector_type(4)));
typedef short s4 __attribute__((ext_vector_type(4)));  // 4 bf16 (2 VGPR)

#define QSCALE 0.1803368801111f  /* 0.125 * log2(e) */

// B=8, N=1025 (32*32+1), DIM=512, HEADS=12, DH=64, INNER=768
// M = 8*1025 = 8200, padded to 8320. KV per (b,h): 1025 = 16*64 + 1 -> 16 full
// tiles + rank-1 tail (kv=1024) handled in-register.
// V layout "vP": per head [kvq=272][d=64][e=4], kv = kvq*4+e.
// PV uses mfma_f32_16x16x16_bf16 whose A-fragment (lane: A[l15][4*l4+e])
// exactly matches the swapped-QK^T P ownership; no cross-lane P movement.
// Softmax: shift-free (scores exp2-domain max ~8.3 -> p<=~300, FP-safe).
// ROUND-16: V must come from LDS. ROUND-18: ones-MFMA denominator loses.
// ROUND-19/20: flash was wave-limited; 8-wave blocks fixed it.
// ROUND-21: gemm0 K-loop is at its 1-phase family ceiling.
// ROUND-24: gemm0's cost is partly the EPILOGUE SCATTER (swapped layout puts
// 16 different rows across lanes -> each q/k uint2 store = ~64 L2 txns).
// 768/128=6 -> each block writes exactly one of {q,k,vP} (seg = tn/6), and
// per head the q/k region is contiguous -> LDS round-trip epilogue gives
// fully coalesced 8B stores (128B runs). vP blocks keep the old path
// (alignment trap, round-8 lesson).

__device__ __forceinline__ void gload_lds16(const void* g, void* l) {
  typedef const __attribute__((address_space(1))) char g_char;
  typedef __attribute__((address_space(3))) char l_char;
  g_char* gp = (g_char*)(uintptr_t)g;
  l_char* lp = (l_char*)(uint32_t)(uintptr_t)l;
  __builtin_amdgcn_global_load_lds(gp, lp, 16, 0, 0);
}

__device__ __forceinline__ float fexp2(float x) {
#if __has_builtin(__builtin_amdgcn_exp2f)
  return __builtin_amdgcn_exp2f(x);
#else
  return exp2f(x);
#endif
}

__device__ __forceinline__ float frcp(float x) {
#if __has_builtin(__builtin_amdgcn_rcpf)
  return __builtin_amdgcn_rcpf(x);
#else
  return 1.f / x;
#endif
}

__device__ __forceinline__ uint32_t pk2(float a, float b) {
  union { bf16 h; unsigned short u; } ua, ub;
  ua.h = (bf16)a; ub.h = (bf16)b;
  return (uint32_t)ua.u | ((uint32_t)ub.u << 16);
}

__device__ __forceinline__ f32x4 pv_mfma(s4 a, s4 b, f32x4 c) {
#if __has_builtin(__builtin_amdgcn_mfma_f32_16x16x16bf16_1k)
  return __builtin_amdgcn_mfma_f32_16x16x16bf16_1k(a, b, c, 0, 0, 0);
#else
  asm volatile("v_mfma_f32_16x16x16_bf16 %0, %1, %2, %0" : "+v"(c) : "v"(a), "v"(b));
  return c;
#endif
}

// FUSED prep + depthwise conv. Blocks [0,2848): vec8 convert — x->xb (pad to
// 8320 rows), w_qkv->bf16, w_out->bf16. 8-elem-unit boundaries: xb 532480
// (src valid 524800), wqkv 147456, wout 49152; total 729088 = 2848*256.
// Blocks [2848,4896): 3x3 depthwise conv (SAME) + cls passthrough -> locb.
__global__ __launch_bounds__(256) void k_prep(const float* __restrict__ x,
                                              const float* __restrict__ wqkv,
                                              const float* __restrict__ wout,
                                              bf16* __restrict__ xb, bf16* __restrict__ wqkvb,
                                              bf16* __restrict__ woutb,
                                              const float* __restrict__ wdw,
                                              bf16* __restrict__ locb) {
  if (blockIdx.x >= 2848) {
    const int lb = blockIdx.x - 2848;          // 0..2047
    const int b = lb >> 8;
    const int y = (lb >> 3) & 31;
    const int xseg = lb & 7;
    const int c = threadIdx.x * 2;
    const int x0 = xseg * 4;
    const bool hm = (y > 0), hp = (y < 31);
    float wa[9], wb[9];
#pragma unroll
    for (int k = 0; k < 9; ++k) {
      wa[k] = wdw[(size_t)c * 9 + k];
      wb[k] = wdw[(size_t)(c + 1) * 9 + k];
    }
    const float* xrow = x + ((size_t)b * 1025 + 1) * 512 + c;
    float A0 = 0.f, B0 = 0.f, A1 = 0.f, B1 = 0.f;
    for (int cc = x0 - 1; cc <= x0 + 4; ++cc) {
      float2 v0 = make_float2(0.f, 0.f), v1 = v0, v2 = v0;
      if (cc >= 0 && cc < 32) {
        v1 = *(const float2*)&xrow[((size_t)y * 32 + cc) * 512];
        if (hm) v0 = *(const float2*)&xrow[((size_t)(y - 1) * 32 + cc) * 512];
        if (hp) v2 = *(const float2*)&xrow[((size_t)(y + 1) * 32 + cc) * 512];
      }
      float t0a = v0.x * wa[0] + v1.x * wa[3] + v2.x * wa[6];
      float t1a = v0.x * wa[1] + v1.x * wa[4] + v2.x * wa[7];
      float t2a = v0.x * wa[2] + v1.x * wa[5] + v2.x * wa[8];
      float t0b = v0.y * wb[0] + v1.y * wb[3] + v2.y * wb[6];
      float t1b = v0.y * wb[1] + v1.y * wb[4] + v2.y * wb[7];
      float t2b = v0.y * wb[2] + v1.y * wb[5] + v2.y * wb[8];
      int oc = cc - 1;
      if (oc >= x0 && oc <= x0 + 3) {
        size_t o = ((size_t)b * 1025 + 1 + y * 32 + oc) * 512 + c;
        *(uint32_t*)&locb[o] = pk2(A0 + t2a, A1 + t2b);
      }
      A0 = B0 + t1a; B0 = t0a;
      A1 = B1 + t1b; B1 = t0b;
    }
    if (y == 0 && xseg == 0) {
      float2 xc = *(const float2*)&x[((size_t)b * 1025) * 512 + c];
      *(uint32_t*)&locb[((size_t)b * 1025) * 512 + c] = pk2(xc.x, xc.y);
    }
    return;
  }
  // ---- vec8 prep branch (u = 8-elem unit index)
  int u = blockIdx.x * 256 + threadIdx.x;
  const float* src = nullptr;
  bf16* dst = nullptr;
  bool zero = false;
  if (u < 532480) {
    if (u >= 524800) zero = true;
    src = x; dst = xb;
  } else if (u < 679936) {
    u -= 532480; src = wqkv; dst = wqkvb;
  } else {
    u -= 679936; src = wout; dst = woutb;
  }
  float4 a = make_float4(0.f, 0.f, 0.f, 0.f), bq = a;
  if (!zero) {
    a  = *(const float4*)&src[(size_t)u * 8];
    bq = *(const float4*)&src[(size_t)u * 8 + 4];
  }
  uint4 p;
  p.x = pk2(a.x, a.y);
  p.y = pk2(a.z, a.w);
  p.z = pk2(bq.x, bq.y);
  p.w = pk2(bq.z, bq.w);
  *(uint4*)&dst[(size_t)u * 8] = p;
}

// Tiled bf16 GEMM, 3-STAGE pipeline (T3+T4): BK=32, triple-buffered LDS,
// counted vmcnt -> prefetch distance 2. Chunk swizzle (row>>1)&3.
// Bijective XCD-chunked 1D grid (m204).
// TPB=512: 8 waves (2x4 grid, wave tile 64x32). TPB=256: 4 waves (2x2).
// EPI=0 (128x128, NTN=18, TPB=512): q/k blocks (tn<12) use a COALESCED
//   LDS round-trip epilogue (per-head contiguous 16KB regions, 8B stores in
//   128B runs); vP blocks (tn>=12) keep the scattered path.
// EPI=1 (128x64, NTN=8, TPB=256): +bias, fp32 out, row<8200. Grid 520.
template <int EPI, int BM, int BN, int NTN, int TPB>
__global__ __launch_bounds__(TPB) void k_gemm(const bf16* __restrict__ A,
                                              const bf16* __restrict__ Bt, int K,
                                              bf16* __restrict__ q, bf16* __restrict__ kk,
                                              bf16* __restrict__ vt,
                                              const float* __restrict__ bias,
                                              float* __restrict__ out) {
  __shared__ __attribute__((aligned(16))) bf16 smem[3 * (BM + BN) * 32];
  constexpr int NWAVE = TPB / 64;
  constexpr int WCN = (NWAVE == 8) ? 4 : 2;   // wave-grid cols
  constexpr int WRN = NWAVE / WCN;            // wave-grid rows (=2)
  constexpr int WROWS = BM / WRN, WCOLS = BN / WCN;
  constexpr int MF = WROWS / 16, NF = WCOLS / 16;
  constexpr int AL = BM / 16 / NWAVE;         // A wave-loads per stage
  constexpr int BL = BN / 16 / NWAVE;         // B wave-loads per stage
  constexpr int LOADS = AL + BL;
  const int tid = threadIdx.x;
  const int lane = tid & 63;
  const int w = tid >> 6;
  const int wr = w / WCN, wc = w % WCN;
  const int l15 = lane & 15, l4 = lane >> 4;

  auto sAb = [&](int bi) { return smem + bi * (BM * 32); };
  auto sBb = [&](int bi) { return smem + 3 * BM * 32 + bi * (BN * 32); };

  const int nwg = gridDim.x;
  const int qq = nwg >> 3, rr = nwg & 7;
  const int xcd = blockIdx.x & 7, idx = blockIdx.x >> 3;
  const int logical = (xcd < rr) ? xcd * (qq + 1) + idx
                                 : rr * (qq + 1) + (xcd - rr) * qq + idx;
  const int tm = logical / NTN, tn = logical - tm * NTN;

  f32x4 acc[MF][NF] = {};

  const int srow = lane >> 2, schunk = lane & 3;
  const int rA = w * (AL * 16) + srow;
  const bf16* aS = A + ((size_t)(tm * BM + rA)) * K + ((schunk ^ ((rA >> 1) & 3)) * 8);
  const int rB = w * (BL * 16) + srow;
  const bf16* bS = Bt + ((size_t)(tn * BN + rB)) * K + ((schunk ^ ((rB >> 1) & 3)) * 8);

  auto STAGE = [&](int bi, int kt) {
    size_t o = (size_t)kt * 32;
#pragma unroll
    for (int i = 0; i < AL; ++i)
      gload_lds16(aS + (size_t)i * 16 * K + o, &sAb(bi)[(w * (AL * 16) + i * 16) * 32]);
#pragma unroll
    for (int i = 0; i < BL; ++i)
      gload_lds16(bS + (size_t)i * 16 * K + o, &sBb(bi)[(w * (BL * 16) + i * 16) * 32]);
  };

  STAGE(0, 0);
  STAGE(1, 1);
  int cur = 0;
  const int Ksteps = K >> 5;
  for (int kt = 0; kt < Ksteps; ++kt) {
    if (kt + 1 < Ksteps) {
      if constexpr (LOADS == 4)      asm volatile("s_waitcnt vmcnt(4)" ::: "memory");
      else if constexpr (LOADS == 3) asm volatile("s_waitcnt vmcnt(3)" ::: "memory");
      else                           asm volatile("s_waitcnt vmcnt(2)" ::: "memory");
    } else {
      asm volatile("s_waitcnt vmcnt(0)" ::: "memory");
    }
    __builtin_amdgcn_s_barrier();
    __builtin_amdgcn_sched_barrier(0);
    if (kt + 2 < Ksteps) {
      int b2 = cur + 2; if (b2 >= 3) b2 -= 3;
      STAGE(b2, kt + 2);
    }

    const bf16* a_ = sAb(cur);
    const bf16* b_ = sBb(cur);
    bf16x8 af[MF], bfr[NF];
#pragma unroll
    for (int mf = 0; mf < MF; ++mf) {
      int row = wr * WROWS + mf * 16 + l15;
      int phys = l4 ^ ((row >> 1) & 3);
      af[mf] = *(const bf16x8*)&a_[row * 32 + phys * 8];
    }
#pragma unroll
    for (int nf = 0; nf < NF; ++nf) {
      int row = wc * WCOLS + nf * 16 + l15;
      int phys = l4 ^ ((row >> 1) & 3);
      bfr[nf] = *(const bf16x8*)&b_[row * 32 + phys * 8];
    }
    __builtin_amdgcn_s_setprio(1);
#pragma unroll
    for (int mf = 0; mf < MF; ++mf)
#pragma unroll
      for (int nf = 0; nf < NF; ++nf)
        acc[mf][nf] =
            __builtin_amdgcn_mfma_f32_16x16x32_bf16(bfr[nf], af[mf], acc[mf][nf], 0, 0, 0);
    __builtin_amdgcn_s_setprio(0);
    ++cur; if (cur >= 3) cur = 0;
  }

  const int RbaseL = tm * BM + wr * WROWS + l15;
  const int CbaseL = tn * BN + wc * WCOLS + l4 * 4;

  if (EPI == 0 && tn < 12) {
    // ---- coalesced q/k epilogue via LDS round-trip ----
    constexpr int PAD = 132;                  // bf16 elems per row (8B-aligned)
    const int seg = tn / 6;                   // 0 = q, 1 = k (tile fits one seg)
    const float scl = seg ? 1.f : QSCALE;
    bf16* ct = smem;                          // [BM][PAD] C-tile
    __syncthreads();                          // K-loop LDS dead everywhere
#pragma unroll
    for (int mf = 0; mf < MF; ++mf) {
      int rl = wr * WROWS + mf * 16 + l15;
#pragma unroll
      for (int nf = 0; nf < NF; ++nf) {
        int cl = wc * WCOLS + nf * 16 + l4 * 4;
        uint2 p;
        p.x = pk2(acc[mf][nf][0] * scl, acc[mf][nf][1] * scl);
        p.y = pk2(acc[mf][nf][2] * scl, acc[mf][nf][3] * scl);
        *(uint2*)&ct[rl * PAD + cl] = p;
      }
    }
    __syncthreads();
    bf16* dst = seg ? kk : q;
    const int h0 = tn * 2 - seg * 12;         // first of the 2 heads in tile
#pragma unroll
    for (int it = 0; it < BM * 32 / TPB; ++it) {
      int u = it * TPB + tid;                 // 8B unit: 32 per row
      int row = u >> 5;
      int R = tm * BM + row;
      if (R >= 8200) continue;
      int b = R / 1025, n = R - b * 1025;     // per-row -> straddle-safe
      int hh = (u >> 4) & 1;
      int d0 = (u & 15) * 4;
      uint2 v = *(const uint2*)&ct[row * PAD + hh * 64 + d0];
      *(uint2*)&dst[(((size_t)b * 12 + h0 + hh) * 1088 + n) * 64 + d0] = v;
    }
    return;
  }

#pragma unroll
  for (int mf = 0; mf < MF; ++mf) {
    int R = RbaseL + mf * 16;
    if (R >= 8200) continue;
    if (EPI == 0) {
      int b = R / 1025;
      int n = R - b * 1025;
      int kvq = n >> 2, e = n & 3;
#pragma unroll
      for (int nf = 0; nf < NF; ++nf) {
        int Cc0 = CbaseL + nf * 16;
        int inner = Cc0 - 1536;               // tn>=12 -> seg 2 (vP) only
        int h = inner >> 6, d0 = inner & 63;
        bf16* vb = &vt[(((size_t)(b * 12 + h) * 272 + kvq) * 64 + d0) * 4 + e];
#pragma unroll
        for (int r = 0; r < 4; ++r) vb[r * 4] = (bf16)acc[mf][nf][r];
      }
    } else {
#pragma unroll
      for (int nf = 0; nf < NF; ++nf) {
        int Cc0 = CbaseL + nf * 16;
        float4 bz = *(const float4*)&bias[Cc0];
        float4 o4;
        o4.x = acc[mf][nf][0] + bz.x;
        o4.y = acc[mf][nf][1] + bz.y;
        o4.z = acc[mf][nf][2] + bz.z;
        o4.w = acc[mf][nf][3] + bz.w;
        *(float4*)&out[(size_t)R * 512 + Cc0] = o4;
      }
    }
  }
}

// Flash attention, swapped-QK^T, double-buffered K/V, shift-free softmax.
// 8 WAVES per block (512 thr), 128 q-rows/block, grid 864 (= 8*108, exact
// XCD-bijective): 4 blocks/CU x 8 waves = 32 waves/CU, single dispatch round.
// 16 full KV tiles + rank-1 tail. PV via mfma_16x16x16 (P in-register).
// Epilogue fuses the depthwise-conv local branch: adds locb for heads h<8.
// LDS = 32768 B. NOTE: no min-waves launch_bounds (round-4 spill lesson).
__global__ __launch_bounds__(512) void k_flash(const bf16* __restrict__ qg,
                                               const bf16* __restrict__ kg,
                                               const bf16* __restrict__ vpg,
                                               const bf16* __restrict__ locb,
                                               bf16* __restrict__ outb) {
  __shared__ __attribute__((aligned(16))) bf16 sK[2][64 * 64];
  __shared__ __attribute__((aligned(16))) bf16 sVP[2][16 * 256];  // 16 kvq x 64 d x 4 e
  const int tid = threadIdx.x, lane = tid & 63, w = tid >> 6;  // w = 0..7
  const int l15 = lane & 15, l4 = lane >> 4;
  // XCD-contiguous mapping: 864 = 8 * 108
  const int wg = blockIdx.x;
  const int logical = (wg & 7) * 108 + (wg >> 3);
  const int bh = logical / 9, qgp = logical - bh * 9;   // 9 q-groups of 128
  const int b = bh / 12, h = bh - b * 12;

  // Q fragments (pre-scaled by QSCALE in the QKV GEMM epilogue)
  size_t qoff = ((size_t)bh * 1088 + qgp * 128 + w * 16 + l15) * 64 + l4 * 8;
  const bf16x8 qf0 = *(const bf16x8*)&qg[qoff];
  const bf16x8 qf1 = *(const bf16x8*)&qg[qoff + 32];

  float lreg = 0.f;  // per-lane partial row sum (reduced in epilogue)
  f32x4 oa[4] = {};

  const int px0 = (l4 ^ (l15 & 7)) * 8;        // K LDS swizzled chunk, ks=0
  const int px1 = ((4 + l4) ^ (l15 & 7)) * 8;  // ks=1

  // Staging: wave w covers K rows [w*8, w*8+8) (1 gload/wave) and V elements
  // [w*512, (w+1)*512) (1 gload/wave). Both tiles advance 4096 elems per t.
  const int rowK = w * 8 + (lane >> 3);
  const int clogK = (lane & 7) ^ (rowK & 7);
  const bf16* kS = kg + ((size_t)bh * 1088 + rowK) * 64 + clogK * 8;
  const bf16* vS = vpg + (size_t)bh * 69632 + w * 512 + lane * 8;
  const int kD = w * 512;   // wave-uniform LDS elem base (lane adds *8)
  const int vD = w * 512;

  auto STAGE = [&](int bi, int t) {
    size_t o = (size_t)t * 4096;
    gload_lds16(kS + o, &sK[bi][kD]);
    gload_lds16(vS + o, &sVP[bi][vD]);
  };

  STAGE(0, 0);
  int cur = 0;

  for (int t = 0; t < 16; ++t) {
    // Wait this tile's loads (issued one full iteration ago), converge. After
    // the barrier all waves consumed buf[cur^1] -> restage is race-free.
    asm volatile("s_waitcnt vmcnt(0)" ::: "memory");
    __builtin_amdgcn_s_barrier();
    __builtin_amdgcn_sched_barrier(0);
    if (t < 15) STAGE(cur ^ 1, t + 1);

    const bf16* kb_ = sK[cur];
    const bf16* vpb = sVP[cur];

    // S^T = K · Q^T : lane holds S[q=l15][kv = jt*16 + l4*4 + r]
    f32x4 sc[4] = {};
    __builtin_amdgcn_s_setprio(1);
#pragma unroll
    for (int jt = 0; jt < 4; ++jt) {
      bf16x8 a0 = *(const bf16x8*)&kb_[(jt * 16 + l15) * 64 + px0];
      sc[jt] = __builtin_amdgcn_mfma_f32_16x16x32_bf16(a0, qf0, sc[jt], 0, 0, 0);
    }
#pragma unroll
    for (int jt = 0; jt < 4; ++jt) {
      bf16x8 a1 = *(const bf16x8*)&kb_[(jt * 16 + l15) * 64 + px1];
      sc[jt] = __builtin_amdgcn_mfma_f32_16x16x32_bf16(a1, qf1, sc[jt], 0, 0, 0);
    }
    __builtin_amdgcn_s_setprio(0);

    // P = exp2(S); pack per-jt into the 16x16x16 A-fragment directly.
    union { uint32_t u[2]; s4 v; } pa[4];
    float lsum = 0.f;
#pragma unroll
    for (int jt = 0; jt < 4; ++jt) {
      float p0 = fexp2(sc[jt][0]);
      float p1 = fexp2(sc[jt][1]);
      float p2 = fexp2(sc[jt][2]);
      float p3 = fexp2(sc[jt][3]);
      lsum += (p0 + p1) + (p2 + p3);
      pa[jt].u[0] = pk2(p0, p1);
      pa[jt].u[1] = pk2(p2, p3);
    }
    lreg += lsum;

    // O += P · V  (16 x mfma_16x16x16, A = in-register P)
    __builtin_amdgcn_s_setprio(1);
#pragma unroll
    for (int jt = 0; jt < 4; ++jt)
#pragma unroll
      for (int db = 0; db < 4; ++db) {
        s4 vf = *(const s4*)&vpb[((jt * 4 + l4) * 64 + db * 16 + l15) * 4];
        oa[db] = pv_mfma(pa[jt].v, vf, oa[db]);
      }
    __builtin_amdgcn_s_setprio(0);
    cur ^= 1;
  }

  // Rank-1 tail: kv = 1024.
  {
    const bf16* k1 = kg + ((size_t)bh * 1088 + 1024) * 64;
    bf16x8 kA = *(const bf16x8*)&k1[l4 * 8];
    bf16x8 kB = *(const bf16x8*)&k1[32 + l4 * 8];
    float s = 0.f;
#pragma unroll
    for (int e = 0; e < 8; ++e)
      s += (float)qf0[e] * (float)kA[e] + (float)qf1[e] * (float)kB[e];
    s += __shfl_xor(s, 16);
    s += __shfl_xor(s, 32);
    float p = fexp2(s);
    if (l4 == 0) lreg += p;  // count once per q-row (epilogue sums l4 copies)
    float pr[4];
#pragma unroll
    for (int r = 0; r < 4; ++r) pr[r] = __shfl(p, l4 * 4 + r);
    const bf16* v1 = vpg + (size_t)bh * 69632 + 65536;  // kvq=256, e=0
#pragma unroll
    for (int db = 0; db < 4; ++db) {
      float vd = (float)v1[(db * 16 + l15) * 4];
#pragma unroll
      for (int r = 0; r < 4; ++r) oa[db][r] += pr[r] * vd;
    }
  }

  float ls = lreg;
  ls += __shfl_xor(ls, 16);
  ls += __shfl_xor(ls, 32);
  float linv = frcp(ls);
#pragma unroll
  for (int r = 0; r < 4; ++r) {
    float ir = __shfl(linv, l4 * 4 + r);
    int n = qgp * 128 + w * 16 + l4 * 4 + r;
    if (n >= 1025) continue;
#pragma unroll
    for (int db = 0; db < 4; ++db) {
      float v = oa[db][r] * ir;
      if (h < 8)
        v += (float)locb[((size_t)b * 1025 + n) * 512 + h * 64 + db * 16 + l15];
      outb[((size_t)b * 1025 + n) * 768 + h * 64 + db * 16 + l15] = (bf16)v;
    }
  }
}

extern "C" void kernel_launch(void* const* d_in, const int* in_sizes, int n_in,
                              void* d_out, int out_size, void* d_ws, size_t ws_size,
                              hipStream_t stream) {
  const float* x = (const float*)d_in[0];
  const float* w_qkv = (const float*)d_in[1];
  const float* w_dw = (const float*)d_in[2];
  const float* w_out = (const float*)d_in[3];
  const float* b_out = (const float*)d_in[4];
  float* out = (float*)d_out;

  char* ws = (char*)d_ws;
  size_t off = 0;
  auto alloc = [&](size_t bytes) {
    char* p = ws + off;
    off = (off + bytes + 255) & ~(size_t)255;
    return p;
  };
  bf16* xb    = (bf16*)alloc((size_t)8320 * 512 * 2);
  bf16* wqkvb = (bf16*)alloc((size_t)2304 * 512 * 2);
  bf16* woutb = (bf16*)alloc((size_t)512 * 768 * 2);
  bf16* qb    = (bf16*)alloc((size_t)96 * 1088 * 64 * 2);
  bf16* kb    = (bf16*)alloc((size_t)96 * 1088 * 64 * 2);
  bf16* vP    = (bf16*)alloc((size_t)96 * 272 * 64 * 4 * 2);  // 69632 elems/head
  bf16* locb  = (bf16*)alloc((size_t)8 * 1025 * 512 * 2);
  bf16* outb  = (bf16*)alloc((size_t)8320 * 768 * 2);

  // Fused prep (vec8: 2848 blocks) + conv (2048 blocks)
  k_prep<<<4896, 256, 0, stream>>>(x, w_qkv, w_out, xb, wqkvb, woutb, w_dw, locb);
  // 1170 = 65*18 blocks (128x128 tiles, 8 waves), XCD-chunked inside kernel
  k_gemm<0, 128, 128, 18, 512><<<1170, 512, 0, stream>>>(xb, wqkvb, 512, qb, kb, vP,
                                                         nullptr, nullptr);
  k_flash<<<864, 512, 0, stream>>>(qb, kb, vP, locb, outb);
  // 520 = 65*8 blocks (128x64 tiles, 4 waves)
  k_gemm<1, 128, 64, 8, 256><<<520, 256, 0, stream>>>(outb, woutb, 768, nullptr, nullptr,
                                                      nullptr, b_out, out);
}